// Round 7
// baseline (450.120 us; speedup 1.0000x reference)
//
#include <hip/hip_runtime.h>
#include <hip/hip_bf16.h>

// Problem constants
#define NN 50000
#define EE 800000
#define NFR 513
#define NMEL 128
#define HC 128      // H*C = 4*32

typedef __bf16 bf16x8 __attribute__((ext_vector_type(8)));
typedef float floatx4 __attribute__((ext_vector_type(4)));

__device__ __forceinline__ unsigned short f2b(float f) {   // RNE fp32->bf16 bits
    unsigned u = __float_as_uint(f);
    u = (u + 0x7FFFu + ((u >> 16) & 1u)) >> 16;
    return (unsigned short)u;
}
__device__ __forceinline__ float b2f(unsigned short s) {
    return __uint_as_float(((unsigned)s) << 16);
}
__device__ __forceinline__ float lexp(float a) {           // exp(leaky_relu(a, 0.2))
    a = a > 0.f ? a : 0.2f * a;
    return __expf(a);
}

__device__ __forceinline__ float ldf(const float* p, long i) { return p[i]; }
__device__ __forceinline__ void stf(float* p, long i, float v) { p[i] = v; }
__device__ __forceinline__ void stf(__hip_bfloat16* p, long i, float v) {
    ((unsigned short*)p)[i] = f2b(v);
}

// ---------------- fp32 vector GEMM (only for tiny fb@Wg). EPI=2: store bf16 transposed, stride 544 ----------------
#define BM 64
#define BN 64
#define BK 16

template<int EPI, typename TA, typename TB, typename TC>
__global__ __launch_bounds__(256) void gemm_k(const TA* __restrict__ A, const TB* __restrict__ B,
                                              TC* __restrict__ C, int M, int Nn, int K,
                                              const float* __restrict__ bias)
{
    __shared__ float As[BK][BM + 4];
    __shared__ float Bs[BK][BN + 4];
    const int t = threadIdx.x;
    const int row0 = blockIdx.x * BM;
    const int col0 = blockIdx.y * BN;
    const int tc = t & 15, tr = t >> 4;
    float acc[4][4] = {};

    for (int kb = 0; kb < K; kb += BK) {
        #pragma unroll
        for (int i = 0; i < 4; ++i) {
            int idx = i * 256 + t;
            int r = idx >> 4, k = idx & 15;
            int gr = row0 + r, gk = kb + k;
            float v = 0.f;
            if (gr < M && gk < K) v = ldf(A, (long)gr * K + gk);
            As[k][r] = v;
        }
        #pragma unroll
        for (int i = 0; i < 4; ++i) {
            int idx = i * 256 + t;
            int c = idx & 63, k = idx >> 6;
            int gk = kb + k, gc = col0 + c;
            float v = 0.f;
            if (gk < K && gc < Nn) v = ldf(B, (long)gk * Nn + gc);
            Bs[k][c] = v;
        }
        __syncthreads();
        #pragma unroll
        for (int kk = 0; kk < BK; ++kk) {
            float4 av = *reinterpret_cast<const float4*>(&As[kk][tr << 2]);
            float4 bv = *reinterpret_cast<const float4*>(&Bs[kk][tc << 2]);
            float a[4] = {av.x, av.y, av.z, av.w};
            float b[4] = {bv.x, bv.y, bv.z, bv.w};
            #pragma unroll
            for (int i = 0; i < 4; ++i)
                #pragma unroll
                for (int j = 0; j < 4; ++j)
                    acc[i][j] += a[i] * b[j];
        }
        __syncthreads();
    }

    #pragma unroll
    for (int i = 0; i < 4; ++i) {
        int gr = row0 + (tr << 2) + i;
        if (gr >= M) continue;
        #pragma unroll
        for (int j = 0; j < 4; ++j) {
            int gc = col0 + (tc << 2) + j;
            if (gc >= Nn) continue;
            float v = acc[i][j];
            if (EPI == 2) {
                stf(C, (long)gc * 544 + gr, v);      // transposed bf16, zero-padded stride
            } else {
                if (EPI == 1) { v += bias[gc]; v = v > 0.f ? v : 0.01f * v; }
                stf(C, (long)gr * Nn + gc, v);
            }
        }
    }
}

// ---------------- transpose-convert: out[n*KP+k] = bf16(in[k*N+n]) ----------------
__global__ void k_trans(const float* __restrict__ in, __hip_bfloat16* __restrict__ outp,
                        int K, int N, int KP)
{
    int id = blockIdx.x * 256 + threadIdx.x;
    if (id >= N * KP) return;
    int n = id / KP, k = id % KP;
    float v = (k < K) ? in[(long)k * N + n] : 0.f;
    ((unsigned short*)outp)[id] = f2b(v);
}

// ---------------- mgemm1: h = x @ fbWg, B LDS-resident in 2 phases, near-barrier-free K-loop ----------------
// R6 de-risk of the R5 design (which used 832 threads / 139 KB LDS and failed to run
// twice): conventional 512-thread blocks, exactly 64 KB LDS. B staged k<256 then
// k<512 (2 barriers between phases); within a phase, 8 K-steps run with NO sync —
// each wave independently streams its 16 A-rows (fp32->bf16 in regs) into MFMA.
// Total 3 barriers vs 34 in the R1 lockstep loop: tests the same hypothesis.
// Epilogue k=512 reads B direct from global (L2-hot, 16B-aligned; B zero-padded to 544).
// LDS: Bs[chunk][col][8bf16]; staging writes linear, compute reads 16 consecutive
// 16B chunks per 16-lane group -> conflict-free. 64 KB -> 2 blocks/CU, 16 waves/CU.
#define KC 32   // chunks per phase (32 chunks x 8 k = 256 k-values; 65,536 B)

__global__ __launch_bounds__(512) void mgemm1(const float* __restrict__ A,
                                              const __hip_bfloat16* __restrict__ Bt,
                                              __hip_bfloat16* __restrict__ C)
{
    __shared__ unsigned short Bs[KC * 128 * 8];   // 65,536 B
    const int t = threadIdx.x;
    const unsigned short* BtU = (const unsigned short*)Bt;

    const int wave = t >> 6, lane = t & 63;
    const int lm = lane & 15, kq = lane >> 4;
    const int row0g = blockIdx.x * 128 + wave * 16;   // 8 waves x 16 rows = 128 rows/block

    const int arow = row0g + lm;
    const bool rv = arow < NN;
    const float* ap = A + (long)arow * NFR;

    floatx4 acc[8];
    #pragma unroll
    for (int j = 0; j < 8; ++j) acc[j] = 0.f;

    for (int ph = 0; ph < 2; ++ph) {
        // protect LDS before overwrite (ph=1): all waves' phase-0 ds_reads are
        // drained into regs by their own lgkmcnt before passing this barrier.
        __syncthreads();
        // stage 4096 16B-chunks with 512 threads (8 iters), write-linear
        #pragma unroll
        for (int g = 0; g < 8; ++g) {
            int i = g * 512 + t;               // 0..4095
            int col = i & 127, chunk = (i >> 7) + ph * KC;
            *reinterpret_cast<uint4*>(&Bs[(size_t)i * 8]) =
                *reinterpret_cast<const uint4*>(BtU + (size_t)col * 544 + chunk * 8);
        }
        __syncthreads();

        // 8 free-running K-steps (k = ph*256 .. ph*256+255)
        #pragma unroll 4
        for (int step = 0; step < 8; ++step) {
            const int k0 = (ph * 8 + step) * 32 + kq * 8;
            union { bf16x8 v; unsigned short u[8]; } af;
            #pragma unroll
            for (int i2 = 0; i2 < 8; ++i2) {
                float fv = rv ? ap[k0 + i2] : 0.f;
                af.u[i2] = f2b(fv);
            }
            const int chunk = step * 4 + kq;   // local 0..31
            #pragma unroll
            for (int j = 0; j < 8; ++j) {
                bf16x8 bf = *reinterpret_cast<const bf16x8*>(&Bs[((size_t)chunk * 128 + j * 16 + lm) * 8]);
                acc[j] = __builtin_amdgcn_mfma_f32_16x16x32_bf16(af.v, bf, acc[j], 0, 0, 0);
            }
        }
    }

    // epilogue: k = 512..519 (global chunk 64+kq) with B read straight from global.
    // Only k=512 is real data (af zero elsewhere; B zero-padded past 513 anyway).
    {
        union { bf16x8 v; unsigned short u[8]; } af;
        #pragma unroll
        for (int i2 = 0; i2 < 8; ++i2) af.u[i2] = 0;
        if (kq == 0 && rv) af.u[0] = f2b(ap[512]);
        #pragma unroll
        for (int j = 0; j < 8; ++j) {
            bf16x8 bf = *reinterpret_cast<const bf16x8*>(BtU + (size_t)(j * 16 + lm) * 544 + (64 + kq) * 8);
            acc[j] = __builtin_amdgcn_mfma_f32_16x16x32_bf16(af.v, bf, acc[j], 0, 0, 0);
        }
    }

    // C[row][col]: row = row0g + kq*4 + r, col = j*16 + lm (verified mapping)
    #pragma unroll
    for (int r = 0; r < 4; ++r) {
        int crow = row0g + kq * 4 + r;
        if (crow >= NN) continue;
        #pragma unroll
        for (int j = 0; j < 8; ++j)
            ((unsigned short*)C)[(long)crow * 128 + j * 16 + lm] = f2b(acc[j][r]);
    }
}

// ---------------- MFMA bf16 GEMM (for #2/#3): C[M,Nn] = A[M,K] @ Bt[Nn,KB]^T ----------------
// R3 geometry (verified): 64x128 tile, double-buffered LDS, reg-staged single-barrier pipeline.
#define PS 40   // LDS row stride in bf16 units (80 B) -> 2-way bank conflicts only (free)

struct ARegsB { uint4 v; };

__device__ __forceinline__ void loadA_r(const __hip_bfloat16* __restrict__ A, ARegsB& r,
                                        int t, int row0, int M, int K, int kb)
{
    int row = t >> 2, k8 = (t & 3) * 8;  // 256 16B-chunks (64 rows x 4)
    int gr = row0 + row;
    uint4 val = make_uint4(0, 0, 0, 0);
    if (gr < M) val = *reinterpret_cast<const uint4*>(A + (long)gr * K + kb + k8);
    r.v = val;
}

__device__ __forceinline__ void writeA_r(unsigned short* As, const ARegsB& r, int t)
{
    int row = t >> 2, k8 = (t & 3) * 8;
    *reinterpret_cast<uint4*>(&As[row * PS + k8]) = r.v;
}

__device__ __forceinline__ void loadB_r(const __hip_bfloat16* __restrict__ Bt, uint4* bR, int t,
                                        int col0, int Nn, int KB, int kb)
{
    #pragma unroll
    for (int g = 0; g < 2; ++g) {
        int c = g * 256 + t;            // 0..511 16B-chunks (128 rows x 4)
        int row = c >> 2, k8 = (c & 3) * 8;
        int gn = col0 + row;
        uint4 val = make_uint4(0, 0, 0, 0);
        if (gn < Nn) val = *reinterpret_cast<const uint4*>(Bt + (long)gn * KB + kb + k8);
        bR[g] = val;
    }
}

__device__ __forceinline__ void writeB_r(unsigned short* Bs, const uint4* bR, int t)
{
    #pragma unroll
    for (int g = 0; g < 2; ++g) {
        int c = g * 256 + t;
        int row = c >> 2, k8 = (c & 3) * 8;
        *reinterpret_cast<uint4*>(&Bs[row * PS + k8]) = bR[g];
    }
}

template<int EPI>
__global__ __launch_bounds__(256) void mgemm(const __hip_bfloat16* __restrict__ A,
                                             const __hip_bfloat16* __restrict__ Bt,
                                             __hip_bfloat16* __restrict__ C,
                                             int M, int Nn, int K, int KB,
                                             const float* __restrict__ bias)
{
    __shared__ unsigned short As[2][64 * PS];
    __shared__ unsigned short Bs[2][128 * PS];
    const int t = threadIdx.x;
    const int row0 = blockIdx.x * 64;
    const int col0 = blockIdx.y * 128;
    const int wave = t >> 6, lane = t & 63;
    const int wm = (wave >> 1) * 32, wn = (wave & 1) * 64;
    const int lm = lane & 15, kq = lane >> 4;

    floatx4 acc[2][4];
    #pragma unroll
    for (int i = 0; i < 2; ++i)
        #pragma unroll
        for (int j = 0; j < 4; ++j)
            acc[i][j] = 0.f;

    ARegsB aR;
    uint4 bR[2];
    loadA_r(A, aR, t, row0, M, K, 0);
    loadB_r(Bt, bR, t, col0, Nn, KB, 0);

    const int nIter = KB >> 5;
    int b = 0;
    for (int it = 0; it < nIter; ++it) {
        writeA_r(As[b], aR, t);
        writeB_r(Bs[b], bR, t);
        if (it + 1 < nIter) {
            loadA_r(A, aR, t, row0, M, K, (it + 1) * 32);
            loadB_r(Bt, bR, t, col0, Nn, KB, (it + 1) * 32);
        }
        asm volatile("s_waitcnt lgkmcnt(0)" ::: "memory");
        __builtin_amdgcn_s_barrier();
        __builtin_amdgcn_sched_barrier(0);

        bf16x8 af[2], bf[4];
        #pragma unroll
        for (int i = 0; i < 2; ++i)
            af[i] = *reinterpret_cast<const bf16x8*>(&As[b][(wm + i * 16 + lm) * PS + kq * 8]);
        #pragma unroll
        for (int j = 0; j < 4; ++j)
            bf[j] = *reinterpret_cast<const bf16x8*>(&Bs[b][(wn + j * 16 + lm) * PS + kq * 8]);
        #pragma unroll
        for (int i = 0; i < 2; ++i)
            #pragma unroll
            for (int j = 0; j < 4; ++j)
                acc[i][j] = __builtin_amdgcn_mfma_f32_16x16x32_bf16(af[i], bf[j], acc[i][j], 0, 0, 0);
        b ^= 1;
    }

    #pragma unroll
    for (int i = 0; i < 2; ++i) {
        #pragma unroll
        for (int r = 0; r < 4; ++r) {
            int gr = row0 + wm + i * 16 + kq * 4 + r;
            if (gr >= M) continue;
            #pragma unroll
            for (int j = 0; j < 4; ++j) {
                int gc = col0 + wn + j * 16 + lm;
                float v = acc[i][j][r];
                if (EPI == 1) { v += bias[gc]; v = v > 0.f ? v : 0.01f * v; }
                stf(C, (long)gr * Nn + gc, v);
            }
        }
    }
}

// ---------------- per-node attention coefficients (h in bf16) ----------------
__global__ void k_att(const __hip_bfloat16* __restrict__ h, const float* __restrict__ att_src,
                      const float* __restrict__ att_dst,
                      float* __restrict__ a_s, float* __restrict__ a_d)
{
    int id = blockIdx.x * blockDim.x + threadIdx.x;
    if (id >= NN * 4) return;
    int n = id >> 2, hh = id & 3;
    const unsigned short* hr = (const unsigned short*)(h + (long)n * HC + hh * 32);
    float s1 = 0.f, s2 = 0.f;
    #pragma unroll
    for (int c = 0; c < 32; ++c) {
        float v = b2f(hr[c]);
        s1 += v * att_src[hh * 32 + c];
        s2 += v * att_dst[hh * 32 + c];
    }
    a_s[id] = s1;
    a_d[id] = s2;
}

// ---------------- CSR build: histogram -> scan -> fill ----------------
__global__ void k_hist(const int* __restrict__ ei, int* __restrict__ hist)
{
    int e = blockIdx.x * 256 + threadIdx.x;
    if (e < EE) atomicAdd(&hist[ei[EE + e]], 1);
}

__global__ __launch_bounds__(512) void k_scan1(const int* __restrict__ hist, int* __restrict__ start,
                                               int* __restrict__ aux)
{
    __shared__ int sm[512];
    int t = threadIdx.x, i = blockIdx.x * 512 + t;
    int v = (i < NN) ? hist[i] : 0;
    sm[t] = v;
    __syncthreads();
    for (int off = 1; off < 512; off <<= 1) {
        int x = (t >= off) ? sm[t - off] : 0;
        __syncthreads();
        sm[t] += x;
        __syncthreads();
    }
    if (i < NN) start[i] = sm[t] - v;   // exclusive
    if (t == 511) aux[blockIdx.x] = sm[511];
}

__global__ void k_scan2(int* __restrict__ aux, int nb)
{
    if (blockIdx.x == 0 && threadIdx.x == 0) {
        int run = 0;
        for (int b = 0; b < nb; ++b) { int v = aux[b]; aux[b] = run; run += v; }
    }
}

__global__ __launch_bounds__(512) void k_scan3(int* __restrict__ start, int* __restrict__ cursor,
                                               const int* __restrict__ aux)
{
    int i = blockIdx.x * 512 + threadIdx.x;
    if (i < NN) {
        int v = start[i] + aux[blockIdx.x];
        start[i] = v;
        cursor[i] = v;
    }
    if (i == 0) start[NN] = EE;
}

__global__ void k_fill(const int* __restrict__ ei, int* __restrict__ cursor, int* __restrict__ sorted)
{
    int e = blockIdx.x * 256 + threadIdx.x;
    if (e >= EE) return;
    int s = ei[e], d = ei[EE + e];
    int pos = atomicAdd(&cursor[d], 1);
    sorted[pos] = s;
}

// ---------------- per-node gather-aggregate, unrolled x4 for memory-level parallelism ----------------
__global__ __launch_bounds__(256) void k_agg(const int* __restrict__ start, const int* __restrict__ sorted,
                                             const float* __restrict__ a_s, const float* __restrict__ a_d,
                                             const __hip_bfloat16* __restrict__ h,
                                             const float* __restrict__ bias_g,
                                             __hip_bfloat16* __restrict__ agg)
{
    int wave = threadIdx.x >> 6;
    int lane = threadIdx.x & 63;
    int d = blockIdx.x * 4 + wave;
    if (d >= NN) return;
    int hh = lane >> 4;                 // head of features 2*lane, 2*lane+1
    float ad = a_d[d * 4 + hh];
    int e0 = start[d], e1 = start[d + 1];

    // self-loop contribution
    float ex = lexp(a_s[d * 4 + hh] + ad);
    unsigned hv = *reinterpret_cast<const unsigned*>(h + (long)d * HC + 2 * lane);
    float acc0 = ex * __uint_as_float(hv << 16);
    float acc1 = ex * __uint_as_float(hv & 0xffff0000u);
    float dsum = ex;

    int e = e0;
    for (; e + 4 <= e1; e += 4) {
        int s0 = sorted[e + 0], s1 = sorted[e + 1], s2 = sorted[e + 2], s3 = sorted[e + 3];
        float as0 = a_s[s0 * 4 + hh], as1 = a_s[s1 * 4 + hh];
        float as2 = a_s[s2 * 4 + hh], as3 = a_s[s3 * 4 + hh];
        unsigned h0 = *reinterpret_cast<const unsigned*>(h + (long)s0 * HC + 2 * lane);
        unsigned h1 = *reinterpret_cast<const unsigned*>(h + (long)s1 * HC + 2 * lane);
        unsigned h2 = *reinterpret_cast<const unsigned*>(h + (long)s2 * HC + 2 * lane);
        unsigned h3 = *reinterpret_cast<const unsigned*>(h + (long)s3 * HC + 2 * lane);
        float x0 = lexp(as0 + ad), x1 = lexp(as1 + ad), x2 = lexp(as2 + ad), x3 = lexp(as3 + ad);
        acc0 += x0 * __uint_as_float(h0 << 16);
        acc1 += x0 * __uint_as_float(h0 & 0xffff0000u);
        acc0 += x1 * __uint_as_float(h1 << 16);
        acc1 += x1 * __uint_as_float(h1 & 0xffff0000u);
        acc0 += x2 * __uint_as_float(h2 << 16);
        acc1 += x2 * __uint_as_float(h2 & 0xffff0000u);
        acc0 += x3 * __uint_as_float(h3 << 16);
        acc1 += x3 * __uint_as_float(h3 & 0xffff0000u);
        dsum += x0 + x1 + x2 + x3;
    }
    for (; e < e1; ++e) {
        int s = sorted[e];
        float xe = lexp(a_s[s * 4 + hh] + ad);
        unsigned hs = *reinterpret_cast<const unsigned*>(h + (long)s * HC + 2 * lane);
        acc0 += xe * __uint_as_float(hs << 16);
        acc1 += xe * __uint_as_float(hs & 0xffff0000u);
        dsum += xe;
    }

    float inv = 1.f / dsum;
    float2 bg = *reinterpret_cast<const float2*>(bias_g + 2 * lane);
    float v0 = acc0 * inv + bg.x;
    float v1 = acc1 * inv + bg.y;
    v0 = v0 > 0.f ? v0 : expm1f(v0);
    v1 = v1 > 0.f ? v1 : expm1f(v1);
    unsigned pk = (unsigned)f2b(v0) | ((unsigned)f2b(v1) << 16);
    *reinterpret_cast<unsigned*>((unsigned short*)agg + (long)d * HC + 2 * lane) = pk;
}

// ---------------- final: leaky(x2@W3+b3) -> softmax -> fp32 out (x2 in bf16) ----------------
__global__ __launch_bounds__(256) void k_final(const __hip_bfloat16* __restrict__ x2, const float* __restrict__ W3,
                                               const float* __restrict__ b3, float* __restrict__ out)
{
    __shared__ float w3s[128 * 10];
    __shared__ float b3s[10];
    int t = threadIdx.x;
    for (int i = t; i < 128 * 10; i += 256) w3s[i] = W3[i];
    if (t < 10) b3s[t] = b3[t];
    __syncthreads();
    int n = blockIdx.x * 256 + t;
    if (n >= NN) return;

    float l[10];
    #pragma unroll
    for (int j = 0; j < 10; ++j) l[j] = b3s[j];
    const uint4* row = reinterpret_cast<const uint4*>(x2 + (long)n * 128);
    #pragma unroll 4
    for (int c8 = 0; c8 < 16; ++c8) {
        uint4 v = row[c8];
        const unsigned w[4] = {v.x, v.y, v.z, v.w};
        #pragma unroll
        for (int u = 0; u < 4; ++u) {
            float f0 = __uint_as_float(w[u] << 16);
            float f1 = __uint_as_float(w[u] & 0xffff0000u);
            const float* wr = &w3s[(c8 * 8 + u * 2) * 10];
            #pragma unroll
            for (int j = 0; j < 10; ++j) l[j] += f0 * wr[j] + f1 * wr[10 + j];
        }
    }
    float m = -1e30f;
    #pragma unroll
    for (int j = 0; j < 10; ++j) {
        float v = l[j];
        v = v > 0.f ? v : 0.01f * v;
        l[j] = v;
        m = fmaxf(m, v);
    }
    float sum = 0.f;
    #pragma unroll
    for (int j = 0; j < 10; ++j) { l[j] = __expf(l[j] - m); sum += l[j]; }
    float inv = 1.f / sum;
    #pragma unroll
    for (int j = 0; j < 10; ++j) out[(long)n * 10 + j] = l[j] * inv;
}

extern "C" void kernel_launch(void* const* d_in, const int* in_sizes, int n_in,
                              void* d_out, int out_size, void* d_ws, size_t ws_size,
                              hipStream_t stream)
{
    const float* x       = (const float*)d_in[0];
    const int*   ei      = (const int*)d_in[1];
    const float* fb      = (const float*)d_in[2];
    const float* Wg      = (const float*)d_in[3];
    const float* bias_g  = (const float*)d_in[4];
    const float* att_src = (const float*)d_in[5];
    const float* att_dst = (const float*)d_in[6];
    const float* W1      = (const float*)d_in[7];
    const float* b1      = (const float*)d_in[8];
    const float* W2      = (const float*)d_in[9];
    const float* b2      = (const float*)d_in[10];
    const float* W3      = (const float*)d_in[11];
    const float* b3      = (const float*)d_in[12];
    float* out = (float*)d_out;
    float* ws = (float*)d_ws;

    // workspace layout (float units) — total 14,167,720 floats = 56.67 MB
    float* a_s = ws + 0;                                        //   200,000 [N,4]
    float* a_d = ws + 200000;                                   //   200,000 [N,4]
    __hip_bfloat16* fbWgT = (__hip_bfloat16*)(ws + 400000);     //   [128][544] bf16 (34,816 f)
    __hip_bfloat16* W1T   = (__hip_bfloat16*)(ws + 434816);     //   [256][128] bf16 (16,384 f)
    __hip_bfloat16* W2T   = (__hip_bfloat16*)(ws + 451200);     //   [128][256] bf16 (16,384 f)
    int* hist   = (int*)(ws + 467584);                          //    50,000 (cursor aliases)
    int* startA = (int*)(ws + 517584);                          //    50,004
    int* aux    = (int*)(ws + 567588);                          //       132
    int* sorted = (int*)(ws + 567720);                          //   800,000
    __hip_bfloat16* hbufB = (__hip_bfloat16*)(ws + 1367720);    //   [N,128] bf16 (3,200,000 f)
    __hip_bfloat16* aggB  = (__hip_bfloat16*)(ws + 4567720);    //   [N,128] bf16 (3,200,000 f)
    __hip_bfloat16* x1B   = (__hip_bfloat16*)(ws + 7767720);    //   [N,256] bf16 (6,400,000 f)
    int* cursor = hist;                                         //   alias (hist dead after scan1)
    __hip_bfloat16* x2B = hbufB;                                //   [N,128] bf16 over dead hbuf
    if (ws_size < (size_t)14167720 * sizeof(float)) return;     //   diagnostic: leaves out zeroed

    // zero fbWgT (for K-pad zeros) .. hist (contiguous region)
    hipMemsetAsync(ws + 400000, 0, (size_t)117584 * sizeof(float), stream);

    // fbWgT = (fb @ Wg)^T as bf16, zero-padded K 513->544
    gemm_k<2, float, float, __hip_bfloat16><<<dim3(9, 2), 256, 0, stream>>>(fb, Wg, fbWgT, NFR, HC, NMEL, nullptr);
    // W1T, W2T: transpose-convert weights
    k_trans<<<128, 256, 0, stream>>>(W1, W1T, 128, 256, 128);
    k_trans<<<128, 256, 0, stream>>>(W2, W2T, 256, 128, 256);

    // h = x @ fbWg   (B LDS-resident in 2 phases, near-barrier-free)  [N,128]
    mgemm1<<<391, 512, 0, stream>>>(x, fbWgT, hbufB);

    // per-node attention coefficients
    k_att<<<(NN * 4 + 255) / 256, 256, 0, stream>>>(hbufB, att_src, att_dst, a_s, a_d);

    // CSR build
    k_hist<<<(EE + 255) / 256, 256, 0, stream>>>(ei, hist);
    k_scan1<<<98, 512, 0, stream>>>(hist, startA, aux);
    k_scan2<<<1, 64, 0, stream>>>(aux, 98);
    k_scan3<<<98, 512, 0, stream>>>(startA, cursor, aux);
    k_fill<<<(EE + 255) / 256, 256, 0, stream>>>(ei, cursor, sorted);

    // gather-aggregate: softmax + messages + bias + ELU -> agg bf16
    k_agg<<<(NN + 3) / 4, 256, 0, stream>>>(startA, sorted, a_s, a_d, hbufB, bias_g, aggB);

    // x1 = leaky(agg @ W1 + b1)   [N,256] bf16
    mgemm<1><<<dim3(782, 2), 256, 0, stream>>>(aggB, W1T, x1B, NN, 256, 128, 128, b1);

    // x2 = leaky(x1 @ W2 + b2)    [N,128] bf16 (over dead hbuf)
    mgemm<1><<<dim3(782, 1), 256, 0, stream>>>(x1B, W2T, x2B, NN, 128, 256, 256, b2);

    // out = softmax(leaky(x2 @ W3 + b3))
    k_final<<<(NN + 255) / 256, 256, 0, stream>>>(x2B, W3, b3, out);
}

// Round 8
// 449.204 us; speedup vs baseline: 1.0020x; 1.0020x over previous
//
#include <hip/hip_runtime.h>
#include <hip/hip_bf16.h>

// Problem constants
#define NN 50000
#define EE 800000
#define NFR 513
#define NMEL 128
#define HC 128      // H*C = 4*32

typedef __bf16 bf16x8 __attribute__((ext_vector_type(8)));
typedef float floatx4 __attribute__((ext_vector_type(4)));

__device__ __forceinline__ unsigned short f2b(float f) {   // RNE fp32->bf16 bits
    unsigned u = __float_as_uint(f);
    u = (u + 0x7FFFu + ((u >> 16) & 1u)) >> 16;
    return (unsigned short)u;
}
__device__ __forceinline__ float b2f(unsigned short s) {
    return __uint_as_float(((unsigned)s) << 16);
}
__device__ __forceinline__ float lexp(float a) {           // exp(leaky_relu(a, 0.2))
    a = a > 0.f ? a : 0.2f * a;
    return __expf(a);
}

__device__ __forceinline__ float ldf(const float* p, long i) { return p[i]; }
__device__ __forceinline__ void stf(float* p, long i, float v) { p[i] = v; }
__device__ __forceinline__ void stf(__hip_bfloat16* p, long i, float v) {
    ((unsigned short*)p)[i] = f2b(v);
}

// ---------------- fp32 vector GEMM (only for tiny fb@Wg). EPI=2: store bf16 transposed, stride 544 ----------------
#define BM 64
#define BN 64
#define BK 16

template<int EPI, typename TA, typename TB, typename TC>
__global__ __launch_bounds__(256) void gemm_k(const TA* __restrict__ A, const TB* __restrict__ B,
                                              TC* __restrict__ C, int M, int Nn, int K,
                                              const float* __restrict__ bias)
{
    __shared__ float As[BK][BM + 4];
    __shared__ float Bs[BK][BN + 4];
    const int t = threadIdx.x;
    const int row0 = blockIdx.x * BM;
    const int col0 = blockIdx.y * BN;
    const int tc = t & 15, tr = t >> 4;
    float acc[4][4] = {};

    for (int kb = 0; kb < K; kb += BK) {
        #pragma unroll
        for (int i = 0; i < 4; ++i) {
            int idx = i * 256 + t;
            int r = idx >> 4, k = idx & 15;
            int gr = row0 + r, gk = kb + k;
            float v = 0.f;
            if (gr < M && gk < K) v = ldf(A, (long)gr * K + gk);
            As[k][r] = v;
        }
        #pragma unroll
        for (int i = 0; i < 4; ++i) {
            int idx = i * 256 + t;
            int c = idx & 63, k = idx >> 6;
            int gk = kb + k, gc = col0 + c;
            float v = 0.f;
            if (gk < K && gc < Nn) v = ldf(B, (long)gk * Nn + gc);
            Bs[k][c] = v;
        }
        __syncthreads();
        #pragma unroll
        for (int kk = 0; kk < BK; ++kk) {
            float4 av = *reinterpret_cast<const float4*>(&As[kk][tr << 2]);
            float4 bv = *reinterpret_cast<const float4*>(&Bs[kk][tc << 2]);
            float a[4] = {av.x, av.y, av.z, av.w};
            float b[4] = {bv.x, bv.y, bv.z, bv.w};
            #pragma unroll
            for (int i = 0; i < 4; ++i)
                #pragma unroll
                for (int j = 0; j < 4; ++j)
                    acc[i][j] += a[i] * b[j];
        }
        __syncthreads();
    }

    #pragma unroll
    for (int i = 0; i < 4; ++i) {
        int gr = row0 + (tr << 2) + i;
        if (gr >= M) continue;
        #pragma unroll
        for (int j = 0; j < 4; ++j) {
            int gc = col0 + (tc << 2) + j;
            if (gc >= Nn) continue;
            float v = acc[i][j];
            if (EPI == 2) {
                stf(C, (long)gc * 544 + gr, v);      // transposed bf16, zero-padded stride
            } else {
                if (EPI == 1) { v += bias[gc]; v = v > 0.f ? v : 0.01f * v; }
                stf(C, (long)gr * Nn + gc, v);
            }
        }
    }
}

// ---------------- transpose-convert: out[n*KP+k] = bf16(in[k*N+n]) ----------------
__global__ void k_trans(const float* __restrict__ in, __hip_bfloat16* __restrict__ outp,
                        int K, int N, int KP)
{
    int id = blockIdx.x * 256 + threadIdx.x;
    if (id >= N * KP) return;
    int n = id / KP, k = id % KP;
    float v = (k < K) ? in[(long)k * N + n] : 0.f;
    ((unsigned short*)outp)[id] = f2b(v);
}

// ---------------- mgemm1: h = x @ fbWg, B LDS-resident (2 phases), 4-deep A-load-ahead ----------------
// R7 post-mortem: VGPR=52 (acc alone is 32) -> zero headroom to buffer loads -> the
// compiler serialized each K-step behind a full exposed memory latency (~11K cyc/step
// measured). Sync structure was never the cap (R1/R3/R4/R7 all ~0.9-1.1 TB/s).
// Fix: explicit 4-step rolling load-ahead (32 dwords/lane in flight = 4x MLP); next
// phase's first 4 load-steps issued BEFORE the B-staging barriers so they overlap it.
// __launch_bounds__(512,4) caps VGPR at 128 (keeps 2 blocks/CU via 64KB LDS); ~90 used.
// LDS: Bs[chunk][col][8bf16]; staging writes linear, compute reads 16 consecutive
// 16B chunks per 16-lane group -> conflict-free (R7 measured 0 conflicts).
#define KC 32   // chunks per phase (32 chunks x 8 k = 256 k-values; 65,536 B)

__global__ __launch_bounds__(512, 4) void mgemm1(const float* __restrict__ A,
                                                 const __hip_bfloat16* __restrict__ Bt,
                                                 __hip_bfloat16* __restrict__ C)
{
    __shared__ unsigned short Bs[KC * 128 * 8];   // 65,536 B
    const int t = threadIdx.x;
    const unsigned short* BtU = (const unsigned short*)Bt;

    const int wave = t >> 6, lane = t & 63;
    const int lm = lane & 15, kq = lane >> 4;
    const int row0g = blockIdx.x * 128 + wave * 16;   // 8 waves x 16 rows = 128 rows/block

    const int arow = row0g + lm;
    const bool rv = arow < NN;
    const float* ap = A + (long)arow * NFR;

    floatx4 acc[8];
    #pragma unroll
    for (int j = 0; j < 8; ++j) acc[j] = 0.f;

    float ab[4][8];   // 4-step rolling A-load-ahead (all indices static under unroll)

    for (int ph = 0; ph < 2; ++ph) {
        // issue the first 4 steps' A-loads for this phase BEFORE the staging
        // barriers — they are LDS-independent and fly across the B-stage.
        #pragma unroll
        for (int g = 0; g < 4; ++g) {
            const int k0 = (ph * 8 + g) * 32 + kq * 8;
            #pragma unroll
            for (int i2 = 0; i2 < 8; ++i2)
                ab[g][i2] = rv ? ap[k0 + i2] : 0.f;
        }

        // protect LDS before overwrite (ph=1): all waves' phase-0 ds_reads are
        // drained into regs by their own lgkmcnt before passing this barrier.
        __syncthreads();
        // stage 4096 16B-chunks with 512 threads (8 iters), write-linear
        #pragma unroll
        for (int g = 0; g < 8; ++g) {
            int i = g * 512 + t;               // 0..4095
            int col = i & 127, chunk = (i >> 7) + ph * KC;
            *reinterpret_cast<uint4*>(&Bs[(size_t)i * 8]) =
                *reinterpret_cast<const uint4*>(BtU + (size_t)col * 544 + chunk * 8);
        }
        __syncthreads();

        // 8 K-steps; step s consumes ab[s&3], then refills it with step s+4
        #pragma unroll
        for (int step = 0; step < 8; ++step) {
            union { bf16x8 v; unsigned short u[8]; } af;
            #pragma unroll
            for (int i2 = 0; i2 < 8; ++i2)
                af.u[i2] = f2b(ab[step & 3][i2]);
            if (step + 4 < 8) {
                const int k0 = (ph * 8 + step + 4) * 32 + kq * 8;
                #pragma unroll
                for (int i2 = 0; i2 < 8; ++i2)
                    ab[step & 3][i2] = rv ? ap[k0 + i2] : 0.f;
            }
            const int chunk = step * 4 + kq;   // local 0..31
            #pragma unroll
            for (int j = 0; j < 8; ++j) {
                bf16x8 bf = *reinterpret_cast<const bf16x8*>(&Bs[((size_t)chunk * 128 + j * 16 + lm) * 8]);
                acc[j] = __builtin_amdgcn_mfma_f32_16x16x32_bf16(af.v, bf, acc[j], 0, 0, 0);
            }
        }
    }

    // epilogue: k = 512..519 (global chunk 64+kq) with B read straight from global.
    // Only k=512 is real data (af zero elsewhere; B zero-padded past 513 anyway).
    {
        union { bf16x8 v; unsigned short u[8]; } af;
        #pragma unroll
        for (int i2 = 0; i2 < 8; ++i2) af.u[i2] = 0;
        if (kq == 0 && rv) af.u[0] = f2b(ap[512]);
        #pragma unroll
        for (int j = 0; j < 8; ++j) {
            bf16x8 bf = *reinterpret_cast<const bf16x8*>(BtU + (size_t)(j * 16 + lm) * 544 + (64 + kq) * 8);
            acc[j] = __builtin_amdgcn_mfma_f32_16x16x32_bf16(af.v, bf, acc[j], 0, 0, 0);
        }
    }

    // C[row][col]: row = row0g + kq*4 + r, col = j*16 + lm (verified mapping)
    #pragma unroll
    for (int r = 0; r < 4; ++r) {
        int crow = row0g + kq * 4 + r;
        if (crow >= NN) continue;
        #pragma unroll
        for (int j = 0; j < 8; ++j)
            ((unsigned short*)C)[(long)crow * 128 + j * 16 + lm] = f2b(acc[j][r]);
    }
}

// ---------------- MFMA bf16 GEMM (for #2/#3): C[M,Nn] = A[M,K] @ Bt[Nn,KB]^T ----------------
// R3 geometry (verified): 64x128 tile, double-buffered LDS, reg-staged single-barrier pipeline.
#define PS 40   // LDS row stride in bf16 units (80 B) -> 2-way bank conflicts only (free)

struct ARegsB { uint4 v; };

__device__ __forceinline__ void loadA_r(const __hip_bfloat16* __restrict__ A, ARegsB& r,
                                        int t, int row0, int M, int K, int kb)
{
    int row = t >> 2, k8 = (t & 3) * 8;  // 256 16B-chunks (64 rows x 4)
    int gr = row0 + row;
    uint4 val = make_uint4(0, 0, 0, 0);
    if (gr < M) val = *reinterpret_cast<const uint4*>(A + (long)gr * K + kb + k8);
    r.v = val;
}

__device__ __forceinline__ void writeA_r(unsigned short* As, const ARegsB& r, int t)
{
    int row = t >> 2, k8 = (t & 3) * 8;
    *reinterpret_cast<uint4*>(&As[row * PS + k8]) = r.v;
}

__device__ __forceinline__ void loadB_r(const __hip_bfloat16* __restrict__ Bt, uint4* bR, int t,
                                        int col0, int Nn, int KB, int kb)
{
    #pragma unroll
    for (int g = 0; g < 2; ++g) {
        int c = g * 256 + t;            // 0..511 16B-chunks (128 rows x 4)
        int row = c >> 2, k8 = (c & 3) * 8;
        int gn = col0 + row;
        uint4 val = make_uint4(0, 0, 0, 0);
        if (gn < Nn) val = *reinterpret_cast<const uint4*>(Bt + (long)gn * KB + kb + k8);
        bR[g] = val;
    }
}

__device__ __forceinline__ void writeB_r(unsigned short* Bs, const uint4* bR, int t)
{
    #pragma unroll
    for (int g = 0; g < 2; ++g) {
        int c = g * 256 + t;
        int row = c >> 2, k8 = (c & 3) * 8;
        *reinterpret_cast<uint4*>(&Bs[row * PS + k8]) = bR[g];
    }
}

template<int EPI>
__global__ __launch_bounds__(256) void mgemm(const __hip_bfloat16* __restrict__ A,
                                             const __hip_bfloat16* __restrict__ Bt,
                                             __hip_bfloat16* __restrict__ C,
                                             int M, int Nn, int K, int KB,
                                             const float* __restrict__ bias)
{
    __shared__ unsigned short As[2][64 * PS];
    __shared__ unsigned short Bs[2][128 * PS];
    const int t = threadIdx.x;
    const int row0 = blockIdx.x * 64;
    const int col0 = blockIdx.y * 128;
    const int wave = t >> 6, lane = t & 63;
    const int wm = (wave >> 1) * 32, wn = (wave & 1) * 64;
    const int lm = lane & 15, kq = lane >> 4;

    floatx4 acc[2][4];
    #pragma unroll
    for (int i = 0; i < 2; ++i)
        #pragma unroll
        for (int j = 0; j < 4; ++j)
            acc[i][j] = 0.f;

    ARegsB aR;
    uint4 bR[2];
    loadA_r(A, aR, t, row0, M, K, 0);
    loadB_r(Bt, bR, t, col0, Nn, KB, 0);

    const int nIter = KB >> 5;
    int b = 0;
    for (int it = 0; it < nIter; ++it) {
        writeA_r(As[b], aR, t);
        writeB_r(Bs[b], bR, t);
        if (it + 1 < nIter) {
            loadA_r(A, aR, t, row0, M, K, (it + 1) * 32);
            loadB_r(Bt, bR, t, col0, Nn, KB, (it + 1) * 32);
        }
        asm volatile("s_waitcnt lgkmcnt(0)" ::: "memory");
        __builtin_amdgcn_s_barrier();
        __builtin_amdgcn_sched_barrier(0);

        bf16x8 af[2], bf[4];
        #pragma unroll
        for (int i = 0; i < 2; ++i)
            af[i] = *reinterpret_cast<const bf16x8*>(&As[b][(wm + i * 16 + lm) * PS + kq * 8]);
        #pragma unroll
        for (int j = 0; j < 4; ++j)
            bf[j] = *reinterpret_cast<const bf16x8*>(&Bs[b][(wn + j * 16 + lm) * PS + kq * 8]);
        #pragma unroll
        for (int i = 0; i < 2; ++i)
            #pragma unroll
            for (int j = 0; j < 4; ++j)
                acc[i][j] = __builtin_amdgcn_mfma_f32_16x16x32_bf16(af[i], bf[j], acc[i][j], 0, 0, 0);
        b ^= 1;
    }

    #pragma unroll
    for (int i = 0; i < 2; ++i) {
        #pragma unroll
        for (int r = 0; r < 4; ++r) {
            int gr = row0 + wm + i * 16 + kq * 4 + r;
            if (gr >= M) continue;
            #pragma unroll
            for (int j = 0; j < 4; ++j) {
                int gc = col0 + wn + j * 16 + lm;
                float v = acc[i][j][r];
                if (EPI == 1) { v += bias[gc]; v = v > 0.f ? v : 0.01f * v; }
                stf(C, (long)gr * Nn + gc, v);
            }
        }
    }
}

// ---------------- per-node attention coefficients (h in bf16) ----------------
__global__ void k_att(const __hip_bfloat16* __restrict__ h, const float* __restrict__ att_src,
                      const float* __restrict__ att_dst,
                      float* __restrict__ a_s, float* __restrict__ a_d)
{
    int id = blockIdx.x * blockDim.x + threadIdx.x;
    if (id >= NN * 4) return;
    int n = id >> 2, hh = id & 3;
    const unsigned short* hr = (const unsigned short*)(h + (long)n * HC + hh * 32);
    float s1 = 0.f, s2 = 0.f;
    #pragma unroll
    for (int c = 0; c < 32; ++c) {
        float v = b2f(hr[c]);
        s1 += v * att_src[hh * 32 + c];
        s2 += v * att_dst[hh * 32 + c];
    }
    a_s[id] = s1;
    a_d[id] = s2;
}

// ---------------- CSR build: histogram -> scan -> fill ----------------
__global__ void k_hist(const int* __restrict__ ei, int* __restrict__ hist)
{
    int e = blockIdx.x * 256 + threadIdx.x;
    if (e < EE) atomicAdd(&hist[ei[EE + e]], 1);
}

__global__ __launch_bounds__(512) void k_scan1(const int* __restrict__ hist, int* __restrict__ start,
                                               int* __restrict__ aux)
{
    __shared__ int sm[512];
    int t = threadIdx.x, i = blockIdx.x * 512 + t;
    int v = (i < NN) ? hist[i] : 0;
    sm[t] = v;
    __syncthreads();
    for (int off = 1; off < 512; off <<= 1) {
        int x = (t >= off) ? sm[t - off] : 0;
        __syncthreads();
        sm[t] += x;
        __syncthreads();
    }
    if (i < NN) start[i] = sm[t] - v;   // exclusive
    if (t == 511) aux[blockIdx.x] = sm[511];
}

__global__ void k_scan2(int* __restrict__ aux, int nb)
{
    if (blockIdx.x == 0 && threadIdx.x == 0) {
        int run = 0;
        for (int b = 0; b < nb; ++b) { int v = aux[b]; aux[b] = run; run += v; }
    }
}

__global__ __launch_bounds__(512) void k_scan3(int* __restrict__ start, int* __restrict__ cursor,
                                               const int* __restrict__ aux)
{
    int i = blockIdx.x * 512 + threadIdx.x;
    if (i < NN) {
        int v = start[i] + aux[blockIdx.x];
        start[i] = v;
        cursor[i] = v;
    }
    if (i == 0) start[NN] = EE;
}

__global__ void k_fill(const int* __restrict__ ei, int* __restrict__ cursor, int* __restrict__ sorted)
{
    int e = blockIdx.x * 256 + threadIdx.x;
    if (e >= EE) return;
    int s = ei[e], d = ei[EE + e];
    int pos = atomicAdd(&cursor[d], 1);
    sorted[pos] = s;
}

// ---------------- per-node gather-aggregate, unrolled x4 for memory-level parallelism ----------------
__global__ __launch_bounds__(256) void k_agg(const int* __restrict__ start, const int* __restrict__ sorted,
                                             const float* __restrict__ a_s, const float* __restrict__ a_d,
                                             const __hip_bfloat16* __restrict__ h,
                                             const float* __restrict__ bias_g,
                                             __hip_bfloat16* __restrict__ agg)
{
    int wave = threadIdx.x >> 6;
    int lane = threadIdx.x & 63;
    int d = blockIdx.x * 4 + wave;
    if (d >= NN) return;
    int hh = lane >> 4;                 // head of features 2*lane, 2*lane+1
    float ad = a_d[d * 4 + hh];
    int e0 = start[d], e1 = start[d + 1];

    // self-loop contribution
    float ex = lexp(a_s[d * 4 + hh] + ad);
    unsigned hv = *reinterpret_cast<const unsigned*>(h + (long)d * HC + 2 * lane);
    float acc0 = ex * __uint_as_float(hv << 16);
    float acc1 = ex * __uint_as_float(hv & 0xffff0000u);
    float dsum = ex;

    int e = e0;
    for (; e + 4 <= e1; e += 4) {
        int s0 = sorted[e + 0], s1 = sorted[e + 1], s2 = sorted[e + 2], s3 = sorted[e + 3];
        float as0 = a_s[s0 * 4 + hh], as1 = a_s[s1 * 4 + hh];
        float as2 = a_s[s2 * 4 + hh], as3 = a_s[s3 * 4 + hh];
        unsigned h0 = *reinterpret_cast<const unsigned*>(h + (long)s0 * HC + 2 * lane);
        unsigned h1 = *reinterpret_cast<const unsigned*>(h + (long)s1 * HC + 2 * lane);
        unsigned h2 = *reinterpret_cast<const unsigned*>(h + (long)s2 * HC + 2 * lane);
        unsigned h3 = *reinterpret_cast<const unsigned*>(h + (long)s3 * HC + 2 * lane);
        float x0 = lexp(as0 + ad), x1 = lexp(as1 + ad), x2 = lexp(as2 + ad), x3 = lexp(as3 + ad);
        acc0 += x0 * __uint_as_float(h0 << 16);
        acc1 += x0 * __uint_as_float(h0 & 0xffff0000u);
        acc0 += x1 * __uint_as_float(h1 << 16);
        acc1 += x1 * __uint_as_float(h1 & 0xffff0000u);
        acc0 += x2 * __uint_as_float(h2 << 16);
        acc1 += x2 * __uint_as_float(h2 & 0xffff0000u);
        acc0 += x3 * __uint_as_float(h3 << 16);
        acc1 += x3 * __uint_as_float(h3 & 0xffff0000u);
        dsum += x0 + x1 + x2 + x3;
    }
    for (; e < e1; ++e) {
        int s = sorted[e];
        float xe = lexp(a_s[s * 4 + hh] + ad);
        unsigned hs = *reinterpret_cast<const unsigned*>(h + (long)s * HC + 2 * lane);
        acc0 += xe * __uint_as_float(hs << 16);
        acc1 += xe * __uint_as_float(hs & 0xffff0000u);
        dsum += xe;
    }

    float inv = 1.f / dsum;
    float2 bg = *reinterpret_cast<const float2*>(bias_g + 2 * lane);
    float v0 = acc0 * inv + bg.x;
    float v1 = acc1 * inv + bg.y;
    v0 = v0 > 0.f ? v0 : expm1f(v0);
    v1 = v1 > 0.f ? v1 : expm1f(v1);
    unsigned pk = (unsigned)f2b(v0) | ((unsigned)f2b(v1) << 16);
    *reinterpret_cast<unsigned*>((unsigned short*)agg + (long)d * HC + 2 * lane) = pk;
}

// ---------------- final: leaky(x2@W3+b3) -> softmax -> fp32 out (x2 in bf16) ----------------
__global__ __launch_bounds__(256) void k_final(const __hip_bfloat16* __restrict__ x2, const float* __restrict__ W3,
                                               const float* __restrict__ b3, float* __restrict__ out)
{
    __shared__ float w3s[128 * 10];
    __shared__ float b3s[10];
    int t = threadIdx.x;
    for (int i = t; i < 128 * 10; i += 256) w3s[i] = W3[i];
    if (t < 10) b3s[t] = b3[t];
    __syncthreads();
    int n = blockIdx.x * 256 + t;
    if (n >= NN) return;

    float l[10];
    #pragma unroll
    for (int j = 0; j < 10; ++j) l[j] = b3s[j];
    const uint4* row = reinterpret_cast<const uint4*>(x2 + (long)n * 128);
    #pragma unroll 4
    for (int c8 = 0; c8 < 16; ++c8) {
        uint4 v = row[c8];
        const unsigned w[4] = {v.x, v.y, v.z, v.w};
        #pragma unroll
        for (int u = 0; u < 4; ++u) {
            float f0 = __uint_as_float(w[u] << 16);
            float f1 = __uint_as_float(w[u] & 0xffff0000u);
            const float* wr = &w3s[(c8 * 8 + u * 2) * 10];
            #pragma unroll
            for (int j = 0; j < 10; ++j) l[j] += f0 * wr[j] + f1 * wr[10 + j];
        }
    }
    float m = -1e30f;
    #pragma unroll
    for (int j = 0; j < 10; ++j) {
        float v = l[j];
        v = v > 0.f ? v : 0.01f * v;
        l[j] = v;
        m = fmaxf(m, v);
    }
    float sum = 0.f;
    #pragma unroll
    for (int j = 0; j < 10; ++j) { l[j] = __expf(l[j] - m); sum += l[j]; }
    float inv = 1.f / sum;
    #pragma unroll
    for (int j = 0; j < 10; ++j) out[(long)n * 10 + j] = l[j] * inv;
}

extern "C" void kernel_launch(void* const* d_in, const int* in_sizes, int n_in,
                              void* d_out, int out_size, void* d_ws, size_t ws_size,
                              hipStream_t stream)
{
    const float* x       = (const float*)d_in[0];
    const int*   ei      = (const int*)d_in[1];
    const float* fb      = (const float*)d_in[2];
    const float* Wg      = (const float*)d_in[3];
    const float* bias_g  = (const float*)d_in[4];
    const float* att_src = (const float*)d_in[5];
    const float* att_dst = (const float*)d_in[6];
    const float* W1      = (const float*)d_in[7];
    const float* b1      = (const float*)d_in[8];
    const float* W2      = (const float*)d_in[9];
    const float* b2      = (const float*)d_in[10];
    const float* W3      = (const float*)d_in[11];
    const float* b3      = (const float*)d_in[12];
    float* out = (float*)d_out;
    float* ws = (float*)d_ws;

    // workspace layout (float units) — total 14,167,720 floats = 56.67 MB
    float* a_s = ws + 0;                                        //   200,000 [N,4]
    float* a_d = ws + 200000;                                   //   200,000 [N,4]
    __hip_bfloat16* fbWgT = (__hip_bfloat16*)(ws + 400000);     //   [128][544] bf16 (34,816 f)
    __hip_bfloat16* W1T   = (__hip_bfloat16*)(ws + 434816);     //   [256][128] bf16 (16,384 f)
    __hip_bfloat16* W2T   = (__hip_bfloat16*)(ws + 451200);     //   [128][256] bf16 (16,384 f)
    int* hist   = (int*)(ws + 467584);                          //    50,000 (cursor aliases)
    int* startA = (int*)(ws + 517584);                          //    50,004
    int* aux    = (int*)(ws + 567588);                          //       132
    int* sorted = (int*)(ws + 567720);                          //   800,000
    __hip_bfloat16* hbufB = (__hip_bfloat16*)(ws + 1367720);    //   [N,128] bf16 (3,200,000 f)
    __hip_bfloat16* aggB  = (__hip_bfloat16*)(ws + 4567720);    //   [N,128] bf16 (3,200,000 f)
    __hip_bfloat16* x1B   = (__hip_bfloat16*)(ws + 7767720);    //   [N,256] bf16 (6,400,000 f)
    int* cursor = hist;                                         //   alias (hist dead after scan1)
    __hip_bfloat16* x2B = hbufB;                                //   [N,128] bf16 over dead hbuf
    if (ws_size < (size_t)14167720 * sizeof(float)) return;     //   diagnostic: leaves out zeroed

    // zero fbWgT (for K-pad zeros) .. hist (contiguous region)
    hipMemsetAsync(ws + 400000, 0, (size_t)117584 * sizeof(float), stream);

    // fbWgT = (fb @ Wg)^T as bf16, zero-padded K 513->544
    gemm_k<2, float, float, __hip_bfloat16><<<dim3(9, 2), 256, 0, stream>>>(fb, Wg, fbWgT, NFR, HC, NMEL, nullptr);
    // W1T, W2T: transpose-convert weights
    k_trans<<<128, 256, 0, stream>>>(W1, W1T, 128, 256, 128);
    k_trans<<<128, 256, 0, stream>>>(W2, W2T, 256, 128, 256);

    // h = x @ fbWg   (B LDS-resident, 4-deep A-load-ahead)  [N,128]
    mgemm1<<<391, 512, 0, stream>>>(x, fbWgT, hbufB);

    // per-node attention coefficients
    k_att<<<(NN * 4 + 255) / 256, 256, 0, stream>>>(hbufB, att_src, att_dst, a_s, a_d);

    // CSR build
    k_hist<<<(EE + 255) / 256, 256, 0, stream>>>(ei, hist);
    k_scan1<<<98, 512, 0, stream>>>(hist, startA, aux);
    k_scan2<<<1, 64, 0, stream>>>(aux, 98);
    k_scan3<<<98, 512, 0, stream>>>(startA, cursor, aux);
    k_fill<<<(EE + 255) / 256, 256, 0, stream>>>(ei, cursor, sorted);

    // gather-aggregate: softmax + messages + bias + ELU -> agg bf16
    k_agg<<<(NN + 3) / 4, 256, 0, stream>>>(startA, sorted, a_s, a_d, hbufB, bias_g, aggB);

    // x1 = leaky(agg @ W1 + b1)   [N,256] bf16
    mgemm<1><<<dim3(782, 2), 256, 0, stream>>>(aggB, W1T, x1B, NN, 256, 128, 128, b1);

    // x2 = leaky(x1 @ W2 + b2)    [N,128] bf16 (over dead hbuf)
    mgemm<1><<<dim3(782, 1), 256, 0, stream>>>(x1B, W2T, x2B, NN, 128, 256, 256, b2);

    // out = softmax(leaky(x2 @ W3 + b3))
    k_final<<<(NN + 255) / 256, 256, 0, stream>>>(x2B, W3, b3, out);
}

// Round 9
// 432.271 us; speedup vs baseline: 1.0413x; 1.0392x over previous
//
#include <hip/hip_runtime.h>
#include <hip/hip_bf16.h>

// Problem constants
#define NN 50000
#define EE 800000
#define NFR 513
#define NMEL 128
#define HC 128      // H*C = 4*32

typedef __bf16 bf16x8 __attribute__((ext_vector_type(8)));
typedef float floatx4 __attribute__((ext_vector_type(4)));

// 16-byte load at 4-byte alignment (x rows are 2052 B = 4B-aligned; gfx950 global
// loads support dword-aligned dwordx4). One instruction = 16 B/lane contiguous.
struct __attribute__((packed, aligned(4))) u4a { unsigned x, y, z, w; };

__device__ __forceinline__ unsigned short f2b(float f) {   // RNE fp32->bf16 bits
    unsigned u = __float_as_uint(f);
    u = (u + 0x7FFFu + ((u >> 16) & 1u)) >> 16;
    return (unsigned short)u;
}
__device__ __forceinline__ unsigned short f2bu(unsigned u) {  // RNE on raw fp32 bits
    u = (u + 0x7FFFu + ((u >> 16) & 1u)) >> 16;
    return (unsigned short)u;
}
__device__ __forceinline__ float b2f(unsigned short s) {
    return __uint_as_float(((unsigned)s) << 16);
}
__device__ __forceinline__ float lexp(float a) {           // exp(leaky_relu(a, 0.2))
    a = a > 0.f ? a : 0.2f * a;
    return __expf(a);
}

__device__ __forceinline__ float ldf(const float* p, long i) { return p[i]; }
__device__ __forceinline__ void stf(float* p, long i, float v) { p[i] = v; }
__device__ __forceinline__ void stf(__hip_bfloat16* p, long i, float v) {
    ((unsigned short*)p)[i] = f2b(v);
}

// ---------------- fp32 vector GEMM (only for tiny fb@Wg). EPI=2: store bf16 transposed, stride 544 ----------------
#define BM 64
#define BN 64
#define BK 16

template<int EPI, typename TA, typename TB, typename TC>
__global__ __launch_bounds__(256) void gemm_k(const TA* __restrict__ A, const TB* __restrict__ B,
                                              TC* __restrict__ C, int M, int Nn, int K,
                                              const float* __restrict__ bias)
{
    __shared__ float As[BK][BM + 4];
    __shared__ float Bs[BK][BN + 4];
    const int t = threadIdx.x;
    const int row0 = blockIdx.x * BM;
    const int col0 = blockIdx.y * BN;
    const int tc = t & 15, tr = t >> 4;
    float acc[4][4] = {};

    for (int kb = 0; kb < K; kb += BK) {
        #pragma unroll
        for (int i = 0; i < 4; ++i) {
            int idx = i * 256 + t;
            int r = idx >> 4, k = idx & 15;
            int gr = row0 + r, gk = kb + k;
            float v = 0.f;
            if (gr < M && gk < K) v = ldf(A, (long)gr * K + gk);
            As[k][r] = v;
        }
        #pragma unroll
        for (int i = 0; i < 4; ++i) {
            int idx = i * 256 + t;
            int c = idx & 63, k = idx >> 6;
            int gk = kb + k, gc = col0 + c;
            float v = 0.f;
            if (gk < K && gc < Nn) v = ldf(B, (long)gk * Nn + gc);
            Bs[k][c] = v;
        }
        __syncthreads();
        #pragma unroll
        for (int kk = 0; kk < BK; ++kk) {
            float4 av = *reinterpret_cast<const float4*>(&As[kk][tr << 2]);
            float4 bv = *reinterpret_cast<const float4*>(&Bs[kk][tc << 2]);
            float a[4] = {av.x, av.y, av.z, av.w};
            float b[4] = {bv.x, bv.y, bv.z, bv.w};
            #pragma unroll
            for (int i = 0; i < 4; ++i)
                #pragma unroll
                for (int j = 0; j < 4; ++j)
                    acc[i][j] += a[i] * b[j];
        }
        __syncthreads();
    }

    #pragma unroll
    for (int i = 0; i < 4; ++i) {
        int gr = row0 + (tr << 2) + i;
        if (gr >= M) continue;
        #pragma unroll
        for (int j = 0; j < 4; ++j) {
            int gc = col0 + (tc << 2) + j;
            if (gc >= Nn) continue;
            float v = acc[i][j];
            if (EPI == 2) {
                stf(C, (long)gc * 544 + gr, v);      // transposed bf16, zero-padded stride
            } else {
                if (EPI == 1) { v += bias[gc]; v = v > 0.f ? v : 0.01f * v; }
                stf(C, (long)gr * Nn + gc, v);
            }
        }
    }
}

// ---------------- transpose-convert: out[n*KP+k] = bf16(in[k*N+n]) ----------------
__global__ void k_trans(const float* __restrict__ in, __hip_bfloat16* __restrict__ outp,
                        int K, int N, int KP)
{
    int id = blockIdx.x * 256 + threadIdx.x;
    if (id >= N * KP) return;
    int n = id / KP, k = id % KP;
    float v = (k < K) ? in[(long)k * N + n] : 0.f;
    ((unsigned short*)outp)[id] = f2b(v);
}

// ---------------- MFMA bf16 GEMM: C[M,Nn] = A[M,K] @ Bt[Nn,KB]^T ----------------
// R3-verified geometry (best measured for all three GEMMs): 64x128 tile, double-
// buffered LDS, reg-staged single-barrier pipeline.
// R9 change: fp32 A-loads are now ONE 16B load per lane (u4a, align-4) instead of
// 4 scalar dwords. R1-R8 ablation: sync/occupancy/MLP all flat at ~0.9-1.1 TB/s;
// the remaining axis is per-instruction coalescing — scalar dword loads with
// row-scattered lanes cost ~16 segment-transactions per line re-touch (TA wall,
// ~130K cyc/CU ~= measured 150-190K). 16B/lane covers 8 rows x 128B contiguous.
#define PS 40   // LDS row stride in bf16 units (80 B) -> 2-way bank conflicts only (free)

template<typename T> struct ARegs;
template<> struct ARegs<float> { unsigned v[8]; };        // raw fp32 bits
template<> struct ARegs<__hip_bfloat16> { uint4 v; };

__device__ __forceinline__ void loadA_r(const float* __restrict__ A, ARegs<float>& r, int t,
                                        int row0, int M, int K, int kb)
{
    #pragma unroll
    for (int g = 0; g < 2; ++g) {
        int q = g * 256 + t;            // 0..511 quads (64 rows x 8 quads of 16B)
        int row = q >> 3, k4 = (q & 7) * 4;
        int gr = row0 + row, gk = kb + k4;
        unsigned f0 = 0, f1 = 0, f2 = 0, f3 = 0;
        if (gr < M) {
            const float* ap = A + (long)gr * K + gk;
            if (gk + 3 < K) {           // vector path: single dwordx4 at 4B alignment
                u4a u = *reinterpret_cast<const u4a*>(ap);
                f0 = u.x; f1 = u.y; f2 = u.z; f3 = u.w;
            } else {                    // K-boundary chunk (last kb iter only)
                if (gk + 0 < K) f0 = __float_as_uint(ap[0]);
                if (gk + 1 < K) f1 = __float_as_uint(ap[1]);
                if (gk + 2 < K) f2 = __float_as_uint(ap[2]);
            }
        }
        r.v[g * 4 + 0] = f0; r.v[g * 4 + 1] = f1;
        r.v[g * 4 + 2] = f2; r.v[g * 4 + 3] = f3;
    }
}

__device__ __forceinline__ void writeA_r(unsigned short* As, const ARegs<float>& r, int t)
{
    #pragma unroll
    for (int g = 0; g < 2; ++g) {
        int q = g * 256 + t;
        int row = q >> 3, k4 = (q & 7) * 4;
        ushort4 pk;
        pk.x = f2bu(r.v[g * 4 + 0]); pk.y = f2bu(r.v[g * 4 + 1]);
        pk.z = f2bu(r.v[g * 4 + 2]); pk.w = f2bu(r.v[g * 4 + 3]);
        *reinterpret_cast<ushort4*>(&As[row * PS + k4]) = pk;
    }
}

__device__ __forceinline__ void loadA_r(const __hip_bfloat16* __restrict__ A, ARegs<__hip_bfloat16>& r,
                                        int t, int row0, int M, int K, int kb)
{
    int row = t >> 2, k8 = (t & 3) * 8;  // 256 16B-chunks (64 rows x 4)
    int gr = row0 + row;
    uint4 val = make_uint4(0, 0, 0, 0);
    if (gr < M) val = *reinterpret_cast<const uint4*>(A + (long)gr * K + kb + k8);
    r.v = val;
}

__device__ __forceinline__ void writeA_r(unsigned short* As, const ARegs<__hip_bfloat16>& r, int t)
{
    int row = t >> 2, k8 = (t & 3) * 8;
    *reinterpret_cast<uint4*>(&As[row * PS + k8]) = r.v;
}

__device__ __forceinline__ void loadB_r(const __hip_bfloat16* __restrict__ Bt, uint4* bR, int t,
                                        int col0, int Nn, int KB, int kb)
{
    #pragma unroll
    for (int g = 0; g < 2; ++g) {
        int c = g * 256 + t;            // 0..511 16B-chunks (128 rows x 4)
        int row = c >> 2, k8 = (c & 3) * 8;
        int gn = col0 + row;
        uint4 val = make_uint4(0, 0, 0, 0);
        if (gn < Nn) val = *reinterpret_cast<const uint4*>(Bt + (long)gn * KB + kb + k8);
        bR[g] = val;
    }
}

__device__ __forceinline__ void writeB_r(unsigned short* Bs, const uint4* bR, int t)
{
    #pragma unroll
    for (int g = 0; g < 2; ++g) {
        int c = g * 256 + t;
        int row = c >> 2, k8 = (c & 3) * 8;
        *reinterpret_cast<uint4*>(&Bs[row * PS + k8]) = bR[g];
    }
}

template<int EPI, typename TA, typename TC>
__global__ __launch_bounds__(256) void mgemm(const TA* __restrict__ A,
                                             const __hip_bfloat16* __restrict__ Bt,
                                             TC* __restrict__ C,
                                             int M, int Nn, int K, int KB,
                                             const float* __restrict__ bias)
{
    __shared__ unsigned short As[2][64 * PS];
    __shared__ unsigned short Bs[2][128 * PS];
    const int t = threadIdx.x;
    const int row0 = blockIdx.x * 64;
    const int col0 = blockIdx.y * 128;
    const int wave = t >> 6, lane = t & 63;
    const int wm = (wave >> 1) * 32, wn = (wave & 1) * 64;
    const int lm = lane & 15, kq = lane >> 4;

    floatx4 acc[2][4];
    #pragma unroll
    for (int i = 0; i < 2; ++i)
        #pragma unroll
        for (int j = 0; j < 4; ++j)
            acc[i][j] = 0.f;

    ARegs<TA> aR;
    uint4 bR[2];
    loadA_r(A, aR, t, row0, M, K, 0);
    loadB_r(Bt, bR, t, col0, Nn, KB, 0);

    const int nIter = KB >> 5;
    int b = 0;
    for (int it = 0; it < nIter; ++it) {
        // stage current tile regs -> LDS buf[b] (compiler inserts vmcnt wait on regs)
        writeA_r(As[b], aR, t);
        writeB_r(Bs[b], bR, t);
        // issue next tile's global loads; they stay in flight across the barrier
        if (it + 1 < nIter) {
            loadA_r(A, aR, t, row0, M, K, (it + 1) * 32);
            loadB_r(Bt, bR, t, col0, Nn, KB, (it + 1) * 32);
        }
        // make ds_writes visible, then raw barrier (NO vmcnt drain)
        asm volatile("s_waitcnt lgkmcnt(0)" ::: "memory");
        __builtin_amdgcn_s_barrier();
        __builtin_amdgcn_sched_barrier(0);

        bf16x8 af[2], bf[4];
        #pragma unroll
        for (int i = 0; i < 2; ++i)
            af[i] = *reinterpret_cast<const bf16x8*>(&As[b][(wm + i * 16 + lm) * PS + kq * 8]);
        #pragma unroll
        for (int j = 0; j < 4; ++j)
            bf[j] = *reinterpret_cast<const bf16x8*>(&Bs[b][(wn + j * 16 + lm) * PS + kq * 8]);
        #pragma unroll
        for (int i = 0; i < 2; ++i)
            #pragma unroll
            for (int j = 0; j < 4; ++j)
                acc[i][j] = __builtin_amdgcn_mfma_f32_16x16x32_bf16(af[i], bf[j], acc[i][j], 0, 0, 0);
        b ^= 1;
    }

    #pragma unroll
    for (int i = 0; i < 2; ++i) {
        #pragma unroll
        for (int r = 0; r < 4; ++r) {
            int gr = row0 + wm + i * 16 + kq * 4 + r;
            if (gr >= M) continue;
            #pragma unroll
            for (int j = 0; j < 4; ++j) {
                int gc = col0 + wn + j * 16 + lm;
                float v = acc[i][j][r];
                if (EPI == 1) { v += bias[gc]; v = v > 0.f ? v : 0.01f * v; }
                stf(C, (long)gr * Nn + gc, v);
            }
        }
    }
}

// ---------------- per-node attention coefficients (h in bf16) ----------------
__global__ void k_att(const __hip_bfloat16* __restrict__ h, const float* __restrict__ att_src,
                      const float* __restrict__ att_dst,
                      float* __restrict__ a_s, float* __restrict__ a_d)
{
    int id = blockIdx.x * blockDim.x + threadIdx.x;
    if (id >= NN * 4) return;
    int n = id >> 2, hh = id & 3;
    const unsigned short* hr = (const unsigned short*)(h + (long)n * HC + hh * 32);
    float s1 = 0.f, s2 = 0.f;
    #pragma unroll
    for (int c = 0; c < 32; ++c) {
        float v = b2f(hr[c]);
        s1 += v * att_src[hh * 32 + c];
        s2 += v * att_dst[hh * 32 + c];
    }
    a_s[id] = s1;
    a_d[id] = s2;
}

// ---------------- CSR build: histogram -> scan -> fill ----------------
__global__ void k_hist(const int* __restrict__ ei, int* __restrict__ hist)
{
    int e = blockIdx.x * 256 + threadIdx.x;
    if (e < EE) atomicAdd(&hist[ei[EE + e]], 1);
}

__global__ __launch_bounds__(512) void k_scan1(const int* __restrict__ hist, int* __restrict__ start,
                                               int* __restrict__ aux)
{
    __shared__ int sm[512];
    int t = threadIdx.x, i = blockIdx.x * 512 + t;
    int v = (i < NN) ? hist[i] : 0;
    sm[t] = v;
    __syncthreads();
    for (int off = 1; off < 512; off <<= 1) {
        int x = (t >= off) ? sm[t - off] : 0;
        __syncthreads();
        sm[t] += x;
        __syncthreads();
    }
    if (i < NN) start[i] = sm[t] - v;   // exclusive
    if (t == 511) aux[blockIdx.x] = sm[511];
}

__global__ void k_scan2(int* __restrict__ aux, int nb)
{
    if (blockIdx.x == 0 && threadIdx.x == 0) {
        int run = 0;
        for (int b = 0; b < nb; ++b) { int v = aux[b]; aux[b] = run; run += v; }
    }
}

__global__ __launch_bounds__(512) void k_scan3(int* __restrict__ start, int* __restrict__ cursor,
                                               const int* __restrict__ aux)
{
    int i = blockIdx.x * 512 + threadIdx.x;
    if (i < NN) {
        int v = start[i] + aux[blockIdx.x];
        start[i] = v;
        cursor[i] = v;
    }
    if (i == 0) start[NN] = EE;
}

__global__ void k_fill(const int* __restrict__ ei, int* __restrict__ cursor, int* __restrict__ sorted)
{
    int e = blockIdx.x * 256 + threadIdx.x;
    if (e >= EE) return;
    int s = ei[e], d = ei[EE + e];
    int pos = atomicAdd(&cursor[d], 1);
    sorted[pos] = s;
}

// ---------------- per-node gather-aggregate, unrolled x4 for memory-level parallelism ----------------
__global__ __launch_bounds__(256) void k_agg(const int* __restrict__ start, const int* __restrict__ sorted,
                                             const float* __restrict__ a_s, const float* __restrict__ a_d,
                                             const __hip_bfloat16* __restrict__ h,
                                             const float* __restrict__ bias_g,
                                             __hip_bfloat16* __restrict__ agg)
{
    int wave = threadIdx.x >> 6;
    int lane = threadIdx.x & 63;
    int d = blockIdx.x * 4 + wave;
    if (d >= NN) return;
    int hh = lane >> 4;                 // head of features 2*lane, 2*lane+1
    float ad = a_d[d * 4 + hh];
    int e0 = start[d], e1 = start[d + 1];

    // self-loop contribution
    float ex = lexp(a_s[d * 4 + hh] + ad);
    unsigned hv = *reinterpret_cast<const unsigned*>(h + (long)d * HC + 2 * lane);
    float acc0 = ex * __uint_as_float(hv << 16);
    float acc1 = ex * __uint_as_float(hv & 0xffff0000u);
    float dsum = ex;

    int e = e0;
    for (; e + 4 <= e1; e += 4) {
        int s0 = sorted[e + 0], s1 = sorted[e + 1], s2 = sorted[e + 2], s3 = sorted[e + 3];
        float as0 = a_s[s0 * 4 + hh], as1 = a_s[s1 * 4 + hh];
        float as2 = a_s[s2 * 4 + hh], as3 = a_s[s3 * 4 + hh];
        unsigned h0 = *reinterpret_cast<const unsigned*>(h + (long)s0 * HC + 2 * lane);
        unsigned h1 = *reinterpret_cast<const unsigned*>(h + (long)s1 * HC + 2 * lane);
        unsigned h2 = *reinterpret_cast<const unsigned*>(h + (long)s2 * HC + 2 * lane);
        unsigned h3 = *reinterpret_cast<const unsigned*>(h + (long)s3 * HC + 2 * lane);
        float x0 = lexp(as0 + ad), x1 = lexp(as1 + ad), x2 = lexp(as2 + ad), x3 = lexp(as3 + ad);
        acc0 += x0 * __uint_as_float(h0 << 16);
        acc1 += x0 * __uint_as_float(h0 & 0xffff0000u);
        acc0 += x1 * __uint_as_float(h1 << 16);
        acc1 += x1 * __uint_as_float(h1 & 0xffff0000u);
        acc0 += x2 * __uint_as_float(h2 << 16);
        acc1 += x2 * __uint_as_float(h2 & 0xffff0000u);
        acc0 += x3 * __uint_as_float(h3 << 16);
        acc1 += x3 * __uint_as_float(h3 & 0xffff0000u);
        dsum += x0 + x1 + x2 + x3;
    }
    for (; e < e1; ++e) {
        int s = sorted[e];
        float xe = lexp(a_s[s * 4 + hh] + ad);
        unsigned hs = *reinterpret_cast<const unsigned*>(h + (long)s * HC + 2 * lane);
        acc0 += xe * __uint_as_float(hs << 16);
        acc1 += xe * __uint_as_float(hs & 0xffff0000u);
        dsum += xe;
    }

    float inv = 1.f / dsum;
    float2 bg = *reinterpret_cast<const float2*>(bias_g + 2 * lane);
    float v0 = acc0 * inv + bg.x;
    float v1 = acc1 * inv + bg.y;
    v0 = v0 > 0.f ? v0 : expm1f(v0);
    v1 = v1 > 0.f ? v1 : expm1f(v1);
    unsigned pk = (unsigned)f2b(v0) | ((unsigned)f2b(v1) << 16);
    *reinterpret_cast<unsigned*>((unsigned short*)agg + (long)d * HC + 2 * lane) = pk;
}

// ---------------- final: leaky(x2@W3+b3) -> softmax -> fp32 out (x2 in bf16) ----------------
__global__ __launch_bounds__(256) void k_final(const __hip_bfloat16* __restrict__ x2, const float* __restrict__ W3,
                                               const float* __restrict__ b3, float* __restrict__ out)
{
    __shared__ float w3s[128 * 10];
    __shared__ float b3s[10];
    int t = threadIdx.x;
    for (int i = t; i < 128 * 10; i += 256) w3s[i] = W3[i];
    if (t < 10) b3s[t] = b3[t];
    __syncthreads();
    int n = blockIdx.x * 256 + t;
    if (n >= NN) return;

    float l[10];
    #pragma unroll
    for (int j = 0; j < 10; ++j) l[j] = b3s[j];
    const uint4* row = reinterpret_cast<const uint4*>(x2 + (long)n * 128);
    #pragma unroll 4
    for (int c8 = 0; c8 < 16; ++c8) {
        uint4 v = row[c8];
        const unsigned w[4] = {v.x, v.y, v.z, v.w};
        #pragma unroll
        for (int u = 0; u < 4; ++u) {
            float f0 = __uint_as_float(w[u] << 16);
            float f1 = __uint_as_float(w[u] & 0xffff0000u);
            const float* wr = &w3s[(c8 * 8 + u * 2) * 10];
            #pragma unroll
            for (int j = 0; j < 10; ++j) l[j] += f0 * wr[j] + f1 * wr[10 + j];
        }
    }
    float m = -1e30f;
    #pragma unroll
    for (int j = 0; j < 10; ++j) {
        float v = l[j];
        v = v > 0.f ? v : 0.01f * v;
        l[j] = v;
        m = fmaxf(m, v);
    }
    float sum = 0.f;
    #pragma unroll
    for (int j = 0; j < 10; ++j) { l[j] = __expf(l[j] - m); sum += l[j]; }
    float inv = 1.f / sum;
    #pragma unroll
    for (int j = 0; j < 10; ++j) out[(long)n * 10 + j] = l[j] * inv;
}

extern "C" void kernel_launch(void* const* d_in, const int* in_sizes, int n_in,
                              void* d_out, int out_size, void* d_ws, size_t ws_size,
                              hipStream_t stream)
{
    const float* x       = (const float*)d_in[0];
    const int*   ei      = (const int*)d_in[1];
    const float* fb      = (const float*)d_in[2];
    const float* Wg      = (const float*)d_in[3];
    const float* bias_g  = (const float*)d_in[4];
    const float* att_src = (const float*)d_in[5];
    const float* att_dst = (const float*)d_in[6];
    const float* W1      = (const float*)d_in[7];
    const float* b1      = (const float*)d_in[8];
    const float* W2      = (const float*)d_in[9];
    const float* b2      = (const float*)d_in[10];
    const float* W3      = (const float*)d_in[11];
    const float* b3      = (const float*)d_in[12];
    float* out = (float*)d_out;
    float* ws = (float*)d_ws;

    // workspace layout (float units) — total 14,167,720 floats = 56.67 MB
    float* a_s = ws + 0;                                        //   200,000 [N,4]
    float* a_d = ws + 200000;                                   //   200,000 [N,4]
    __hip_bfloat16* fbWgT = (__hip_bfloat16*)(ws + 400000);     //   [128][544] bf16 (34,816 f)
    __hip_bfloat16* W1T   = (__hip_bfloat16*)(ws + 434816);     //   [256][128] bf16 (16,384 f)
    __hip_bfloat16* W2T   = (__hip_bfloat16*)(ws + 451200);     //   [128][256] bf16 (16,384 f)
    int* hist   = (int*)(ws + 467584);                          //    50,000 (cursor aliases)
    int* startA = (int*)(ws + 517584);                          //    50,004
    int* aux    = (int*)(ws + 567588);                          //       132
    int* sorted = (int*)(ws + 567720);                          //   800,000
    __hip_bfloat16* hbufB = (__hip_bfloat16*)(ws + 1367720);    //   [N,128] bf16 (3,200,000 f)
    __hip_bfloat16* aggB  = (__hip_bfloat16*)(ws + 4567720);    //   [N,128] bf16 (3,200,000 f)
    __hip_bfloat16* x1B   = (__hip_bfloat16*)(ws + 7767720);    //   [N,256] bf16 (6,400,000 f)
    int* cursor = hist;                                         //   alias (hist dead after scan1)
    __hip_bfloat16* x2B = hbufB;                                //   [N,128] bf16 over dead hbuf
    if (ws_size < (size_t)14167720 * sizeof(float)) return;     //   diagnostic: leaves out zeroed

    // zero fbWgT (for K-pad zeros) .. hist (contiguous region)
    hipMemsetAsync(ws + 400000, 0, (size_t)117584 * sizeof(float), stream);

    // fbWgT = (fb @ Wg)^T as bf16, zero-padded K 513->544
    gemm_k<2, float, float, __hip_bfloat16><<<dim3(9, 2), 256, 0, stream>>>(fb, Wg, fbWgT, NFR, HC, NMEL, nullptr);
    // W1T, W2T: transpose-convert weights
    k_trans<<<128, 256, 0, stream>>>(W1, W1T, 128, 256, 128);
    k_trans<<<128, 256, 0, stream>>>(W2, W2T, 256, 128, 256);

    // h = x @ fbWg   (MFMA bf16; A fp32 via 16B u4a loads)  [N,128]
    mgemm<0, float, __hip_bfloat16><<<dim3(782, 1), 256, 0, stream>>>(x, fbWgT, hbufB, NN, HC, NFR, 544, nullptr);

    // per-node attention coefficients
    k_att<<<(NN * 4 + 255) / 256, 256, 0, stream>>>(hbufB, att_src, att_dst, a_s, a_d);

    // CSR build
    k_hist<<<(EE + 255) / 256, 256, 0, stream>>>(ei, hist);
    k_scan1<<<98, 512, 0, stream>>>(hist, startA, aux);
    k_scan2<<<1, 64, 0, stream>>>(aux, 98);
    k_scan3<<<98, 512, 0, stream>>>(startA, cursor, aux);
    k_fill<<<(EE + 255) / 256, 256, 0, stream>>>(ei, cursor, sorted);

    // gather-aggregate: softmax + messages + bias + ELU -> agg bf16
    k_agg<<<(NN + 3) / 4, 256, 0, stream>>>(startA, sorted, a_s, a_d, hbufB, bias_g, aggB);

    // x1 = leaky(agg @ W1 + b1)   [N,256] bf16
    mgemm<1, __hip_bfloat16, __hip_bfloat16><<<dim3(782, 2), 256, 0, stream>>>(aggB, W1T, x1B, NN, 256, 128, 128, b1);

    // x2 = leaky(x1 @ W2 + b2)    [N,128] bf16 (over dead hbuf)
    mgemm<1, __hip_bfloat16, __hip_bfloat16><<<dim3(782, 1), 256, 0, stream>>>(x1B, W2T, x2B, NN, 128, 256, 256, b2);

    // out = softmax(leaky(x2 @ W3 + b3))
    k_final<<<(NN + 255) / 256, 256, 0, stream>>>(x2B, W3, b3, out);
}

// Round 11
// 408.917 us; speedup vs baseline: 1.1008x; 1.0571x over previous
//
#include <hip/hip_runtime.h>
#include <hip/hip_bf16.h>

// Problem constants
#define NN 50000
#define EE 800000
#define NFR 513
#define NMEL 128
#define HC 128      // H*C = 4*32

typedef __bf16 bf16x8 __attribute__((ext_vector_type(8)));
typedef float floatx4 __attribute__((ext_vector_type(4)));

// 16-byte load at 4-byte alignment (x rows are 2052 B = 4B-aligned)
struct __attribute__((packed, aligned(4))) u4a { unsigned x, y, z, w; };

__device__ __forceinline__ unsigned short f2b(float f) {   // RNE fp32->bf16 bits
    unsigned u = __float_as_uint(f);
    u = (u + 0x7FFFu + ((u >> 16) & 1u)) >> 16;
    return (unsigned short)u;
}
__device__ __forceinline__ unsigned short f2bu(unsigned u) {  // RNE on raw fp32 bits
    u = (u + 0x7FFFu + ((u >> 16) & 1u)) >> 16;
    return (unsigned short)u;
}
__device__ __forceinline__ float b2f(unsigned short s) {
    return __uint_as_float(((unsigned)s) << 16);
}
__device__ __forceinline__ float lexp(float a) {           // exp(leaky_relu(a, 0.2))
    a = a > 0.f ? a : 0.2f * a;
    return __expf(a);
}

__device__ __forceinline__ float ldf(const float* p, long i) { return p[i]; }
__device__ __forceinline__ void stf(float* p, long i, float v) { p[i] = v; }
__device__ __forceinline__ void stf(__hip_bfloat16* p, long i, float v) {
    ((unsigned short*)p)[i] = f2b(v);
}

// ---------------- fp32 vector GEMM (only for tiny fb@Wg). EPI=2: store bf16 transposed, stride 544 ----------------
#define BM 64
#define BN 64
#define BK 16

template<int EPI, typename TA, typename TB, typename TC>
__global__ __launch_bounds__(256) void gemm_k(const TA* __restrict__ A, const TB* __restrict__ B,
                                              TC* __restrict__ C, int M, int Nn, int K,
                                              const float* __restrict__ bias)
{
    __shared__ float As[BK][BM + 4];
    __shared__ float Bs[BK][BN + 4];
    const int t = threadIdx.x;
    const int row0 = blockIdx.x * BM;
    const int col0 = blockIdx.y * BN;
    const int tc = t & 15, tr = t >> 4;
    float acc[4][4] = {};

    for (int kb = 0; kb < K; kb += BK) {
        #pragma unroll
        for (int i = 0; i < 4; ++i) {
            int idx = i * 256 + t;
            int r = idx >> 4, k = idx & 15;
            int gr = row0 + r, gk = kb + k;
            float v = 0.f;
            if (gr < M && gk < K) v = ldf(A, (long)gr * K + gk);
            As[k][r] = v;
        }
        #pragma unroll
        for (int i = 0; i < 4; ++i) {
            int idx = i * 256 + t;
            int c = idx & 63, k = idx >> 6;
            int gk = kb + k, gc = col0 + c;
            float v = 0.f;
            if (gk < K && gc < Nn) v = ldf(B, (long)gk * Nn + gc);
            Bs[k][c] = v;
        }
        __syncthreads();
        #pragma unroll
        for (int kk = 0; kk < BK; ++kk) {
            float4 av = *reinterpret_cast<const float4*>(&As[kk][tr << 2]);
            float4 bv = *reinterpret_cast<const float4*>(&Bs[kk][tc << 2]);
            float a[4] = {av.x, av.y, av.z, av.w};
            float b[4] = {bv.x, bv.y, bv.z, bv.w};
            #pragma unroll
            for (int i = 0; i < 4; ++i)
                #pragma unroll
                for (int j = 0; j < 4; ++j)
                    acc[i][j] += a[i] * b[j];
        }
        __syncthreads();
    }

    #pragma unroll
    for (int i = 0; i < 4; ++i) {
        int gr = row0 + (tr << 2) + i;
        if (gr >= M) continue;
        #pragma unroll
        for (int j = 0; j < 4; ++j) {
            int gc = col0 + (tc << 2) + j;
            if (gc >= Nn) continue;
            float v = acc[i][j];
            if (EPI == 2) {
                stf(C, (long)gc * 544 + gr, v);      // transposed bf16, zero-padded stride
            } else {
                if (EPI == 1) { v += bias[gc]; v = v > 0.f ? v : 0.01f * v; }
                stf(C, (long)gr * Nn + gc, v);
            }
        }
    }
}

// ---------------- transpose-convert: out[n*KP+k] = bf16(in[k*N+n]) ----------------
__global__ void k_trans(const float* __restrict__ in, __hip_bfloat16* __restrict__ outp,
                        int K, int N, int KP)
{
    int id = blockIdx.x * 256 + threadIdx.x;
    if (id >= N * KP) return;
    int n = id / KP, k = id % KP;
    float v = (k < K) ? in[(long)k * N + n] : 0.f;
    ((unsigned short*)outp)[id] = f2b(v);
}

// ---------------- MFMA bf16 GEMM: C[M,Nn] = A[M,K] @ Bt[Nn,KB]^T ----------------
// R3/R9 structure (best measured after 9 rounds of ablation; mgemm#1 is at its
// structural floor ~62us — sync/occupancy/MLP/load-width all flat).
// R10 fusions (epilogue reuses the VERIFIED C/D mapping row=wm+i*16+kq*4+r,
// col=wn+j*16+lm):
//   EPI=4: plain C write + fused k_att — per-(i,r) shfl_xor(1,2,4,8) reduction
//          over the 16-lane col group yields a_s/a_d directly from acc.
//   EPI=3: bias+leaky -> LDS x2 tile (64x130 pad) + LDS W3; after barrier,
//          64 threads do the 10-dim matvec + leaky + softmax -> out.
// (R10 bench was a container/acquire failure — audited both fusion paths for
// hang/OOB: LDS 52.5KB, all barriers uniform, all indices bounded. Resubmitting
// unchanged per the R2 precedent.)
#define PS 40   // LDS row stride in bf16 units (80 B) -> 2-way bank conflicts only (free)

template<typename T> struct ARegs;
template<> struct ARegs<float> { unsigned v[8]; };        // raw fp32 bits
template<> struct ARegs<__hip_bfloat16> { uint4 v; };

__device__ __forceinline__ void loadA_r(const float* __restrict__ A, ARegs<float>& r, int t,
                                        int row0, int M, int K, int kb)
{
    #pragma unroll
    for (int g = 0; g < 2; ++g) {
        int q = g * 256 + t;            // 0..511 quads (64 rows x 8 quads of 16B)
        int row = q >> 3, k4 = (q & 7) * 4;
        int gr = row0 + row, gk = kb + k4;
        unsigned f0 = 0, f1 = 0, f2 = 0, f3 = 0;
        if (gr < M) {
            const float* ap = A + (long)gr * K + gk;
            if (gk + 3 < K) {           // vector path: single dwordx4 at 4B alignment
                u4a u = *reinterpret_cast<const u4a*>(ap);
                f0 = u.x; f1 = u.y; f2 = u.z; f3 = u.w;
            } else {                    // K-boundary chunk (last kb iter only)
                if (gk + 0 < K) f0 = __float_as_uint(ap[0]);
                if (gk + 1 < K) f1 = __float_as_uint(ap[1]);
                if (gk + 2 < K) f2 = __float_as_uint(ap[2]);
            }
        }
        r.v[g * 4 + 0] = f0; r.v[g * 4 + 1] = f1;
        r.v[g * 4 + 2] = f2; r.v[g * 4 + 3] = f3;
    }
}

__device__ __forceinline__ void writeA_r(unsigned short* As, const ARegs<float>& r, int t)
{
    #pragma unroll
    for (int g = 0; g < 2; ++g) {
        int q = g * 256 + t;
        int row = q >> 3, k4 = (q & 7) * 4;
        ushort4 pk;
        pk.x = f2bu(r.v[g * 4 + 0]); pk.y = f2bu(r.v[g * 4 + 1]);
        pk.z = f2bu(r.v[g * 4 + 2]); pk.w = f2bu(r.v[g * 4 + 3]);
        *reinterpret_cast<ushort4*>(&As[row * PS + k4]) = pk;
    }
}

__device__ __forceinline__ void loadA_r(const __hip_bfloat16* __restrict__ A, ARegs<__hip_bfloat16>& r,
                                        int t, int row0, int M, int K, int kb)
{
    int row = t >> 2, k8 = (t & 3) * 8;  // 256 16B-chunks (64 rows x 4)
    int gr = row0 + row;
    uint4 val = make_uint4(0, 0, 0, 0);
    if (gr < M) val = *reinterpret_cast<const uint4*>(A + (long)gr * K + kb + k8);
    r.v = val;
}

__device__ __forceinline__ void writeA_r(unsigned short* As, const ARegs<__hip_bfloat16>& r, int t)
{
    int row = t >> 2, k8 = (t & 3) * 8;
    *reinterpret_cast<uint4*>(&As[row * PS + k8]) = r.v;
}

__device__ __forceinline__ void loadB_r(const __hip_bfloat16* __restrict__ Bt, uint4* bR, int t,
                                        int col0, int Nn, int KB, int kb)
{
    #pragma unroll
    for (int g = 0; g < 2; ++g) {
        int c = g * 256 + t;            // 0..511 16B-chunks (128 rows x 4)
        int row = c >> 2, k8 = (c & 3) * 8;
        int gn = col0 + row;
        uint4 val = make_uint4(0, 0, 0, 0);
        if (gn < Nn) val = *reinterpret_cast<const uint4*>(Bt + (long)gn * KB + kb + k8);
        bR[g] = val;
    }
}

__device__ __forceinline__ void writeB_r(unsigned short* Bs, const uint4* bR, int t)
{
    #pragma unroll
    for (int g = 0; g < 2; ++g) {
        int c = g * 256 + t;
        int row = c >> 2, k8 = (c & 3) * 8;
        *reinterpret_cast<uint4*>(&Bs[row * PS + k8]) = bR[g];
    }
}

// EPI: 1 = bias+leaky -> C; 4 = plain C + fused attention coeffs (pf1=att_src,
// pf2=att_dst, po1=a_s, po2=a_d); 3 = bias+leaky -> LDS + fused final matvec+
// softmax (pf1=W3, pf2=b3, po1=out).
template<int EPI, typename TA, typename TC>
__global__ __launch_bounds__(256) void mgemm(const TA* __restrict__ A,
                                             const __hip_bfloat16* __restrict__ Bt,
                                             TC* __restrict__ C,
                                             int M, int Nn, int K, int KB,
                                             const float* __restrict__ bias,
                                             const float* __restrict__ pf1,
                                             const float* __restrict__ pf2,
                                             float* __restrict__ po1,
                                             float* __restrict__ po2)
{
    __shared__ unsigned short As[2][64 * PS];
    __shared__ unsigned short Bs[2][128 * PS];
    __shared__ unsigned short x2s[(EPI == 3) ? 64 * 130 : 2];   // padded 130 -> conflict-free row reads
    __shared__ float w3s[(EPI == 3) ? 1280 : 1];

    const int t = threadIdx.x;
    const int row0 = blockIdx.x * 64;
    const int col0 = blockIdx.y * 128;
    const int wave = t >> 6, lane = t & 63;
    const int wm = (wave >> 1) * 32, wn = (wave & 1) * 64;
    const int lm = lane & 15, kq = lane >> 4;

    if (EPI == 3) {
        for (int i = t; i < 1280; i += 256) w3s[i] = pf1[i];    // W3 [128][10]
    }

    floatx4 acc[2][4];
    #pragma unroll
    for (int i = 0; i < 2; ++i)
        #pragma unroll
        for (int j = 0; j < 4; ++j)
            acc[i][j] = 0.f;

    ARegs<TA> aR;
    uint4 bR[2];
    loadA_r(A, aR, t, row0, M, K, 0);
    loadB_r(Bt, bR, t, col0, Nn, KB, 0);

    const int nIter = KB >> 5;
    int b = 0;
    for (int it = 0; it < nIter; ++it) {
        writeA_r(As[b], aR, t);
        writeB_r(Bs[b], bR, t);
        if (it + 1 < nIter) {
            loadA_r(A, aR, t, row0, M, K, (it + 1) * 32);
            loadB_r(Bt, bR, t, col0, Nn, KB, (it + 1) * 32);
        }
        asm volatile("s_waitcnt lgkmcnt(0)" ::: "memory");
        __builtin_amdgcn_s_barrier();
        __builtin_amdgcn_sched_barrier(0);

        bf16x8 af[2], bf[4];
        #pragma unroll
        for (int i = 0; i < 2; ++i)
            af[i] = *reinterpret_cast<const bf16x8*>(&As[b][(wm + i * 16 + lm) * PS + kq * 8]);
        #pragma unroll
        for (int j = 0; j < 4; ++j)
            bf[j] = *reinterpret_cast<const bf16x8*>(&Bs[b][(wn + j * 16 + lm) * PS + kq * 8]);
        #pragma unroll
        for (int i = 0; i < 2; ++i)
            #pragma unroll
            for (int j = 0; j < 4; ++j)
                acc[i][j] = __builtin_amdgcn_mfma_f32_16x16x32_bf16(af[i], bf[j], acc[i][j], 0, 0, 0);
        b ^= 1;
    }

    // ---- epilogue: C write (global or LDS) ----
    #pragma unroll
    for (int i = 0; i < 2; ++i) {
        #pragma unroll
        for (int r = 0; r < 4; ++r) {
            int lrow = wm + i * 16 + kq * 4 + r;
            int gr = row0 + lrow;
            if (gr >= M) continue;
            #pragma unroll
            for (int j = 0; j < 4; ++j) {
                int gc = col0 + wn + j * 16 + lm;
                float v = acc[i][j][r];
                if (EPI == 1 || EPI == 3) { v += bias[gc]; v = v > 0.f ? v : 0.01f * v; }
                if (EPI == 3) x2s[lrow * 130 + gc] = f2b(v);
                else stf(C, (long)gr * Nn + gc, v);
            }
        }
    }

    // ---- EPI=4: fused attention coefficients from acc ----
    if (EPI == 4) {
        float wsv[4], wdv[4];
        #pragma unroll
        for (int j = 0; j < 4; ++j) {
            int gc = wn + j * 16 + lm;      // col0 == 0 for mgemm#1
            wsv[j] = pf1[gc];
            wdv[j] = pf2[gc];
        }
        #pragma unroll
        for (int i = 0; i < 2; ++i) {
            #pragma unroll
            for (int r = 0; r < 4; ++r) {
                float s0 = acc[i][0][r] * wsv[0] + acc[i][1][r] * wsv[1];   // head wn>>5
                float s1 = acc[i][2][r] * wsv[2] + acc[i][3][r] * wsv[3];   // head (wn>>5)+1
                float d0 = acc[i][0][r] * wdv[0] + acc[i][1][r] * wdv[1];
                float d1 = acc[i][2][r] * wdv[2] + acc[i][3][r] * wdv[3];
                #pragma unroll
                for (int m = 1; m < 16; m <<= 1) {
                    s0 += __shfl_xor(s0, m); s1 += __shfl_xor(s1, m);
                    d0 += __shfl_xor(d0, m); d1 += __shfl_xor(d1, m);
                }
                if (lm == 0) {
                    int grow = row0 + wm + i * 16 + kq * 4 + r;
                    if (grow < M) {
                        int h0 = wn >> 5;                 // 0 or 2
                        po1[grow * 4 + h0]     = s0;
                        po1[grow * 4 + h0 + 1] = s1;
                        po2[grow * 4 + h0]     = d0;
                        po2[grow * 4 + h0 + 1] = d1;
                    }
                }
            }
        }
    }

    // ---- EPI=3: fused final layer (x2 @ W3 + b3 -> leaky -> softmax -> out) ----
    if (EPI == 3) {
        __syncthreads();    // x2s tile complete
        if (t < 64) {
            int grow = row0 + t;
            if (grow < M) {
                float l[10];
                #pragma unroll
                for (int j = 0; j < 10; ++j) l[j] = pf2[j];     // b3
                #pragma unroll 8
                for (int c = 0; c < 128; ++c) {
                    float xv = b2f(x2s[t * 130 + c]);
                    const float* wr = &w3s[c * 10];
                    #pragma unroll
                    for (int j = 0; j < 10; ++j) l[j] += xv * wr[j];
                }
                float m = -1e30f;
                #pragma unroll
                for (int j = 0; j < 10; ++j) {
                    float v = l[j];
                    v = v > 0.f ? v : 0.01f * v;
                    l[j] = v;
                    m = fmaxf(m, v);
                }
                float sum = 0.f;
                #pragma unroll
                for (int j = 0; j < 10; ++j) { l[j] = __expf(l[j] - m); sum += l[j]; }
                float inv = 1.f / sum;
                #pragma unroll
                for (int j = 0; j < 10; ++j) po1[(long)grow * 10 + j] = l[j] * inv;
            }
        }
    }
}

// ---------------- CSR build: histogram -> scan -> fill ----------------
__global__ void k_hist(const int* __restrict__ ei, int* __restrict__ hist)
{
    int e = blockIdx.x * 256 + threadIdx.x;
    if (e < EE) atomicAdd(&hist[ei[EE + e]], 1);
}

__global__ __launch_bounds__(512) void k_scan1(const int* __restrict__ hist, int* __restrict__ start,
                                               int* __restrict__ aux)
{
    __shared__ int sm[512];
    int t = threadIdx.x, i = blockIdx.x * 512 + t;
    int v = (i < NN) ? hist[i] : 0;
    sm[t] = v;
    __syncthreads();
    for (int off = 1; off < 512; off <<= 1) {
        int x = (t >= off) ? sm[t - off] : 0;
        __syncthreads();
        sm[t] += x;
        __syncthreads();
    }
    if (i < NN) start[i] = sm[t] - v;   // exclusive
    if (t == 511) aux[blockIdx.x] = sm[511];
}

// wave-parallel exclusive scan of 98 block sums (was: serial single-thread loop
// doing 98 dependent global round-trips ~ 25us of pure latency)
__global__ void k_scan2(int* __restrict__ aux, int nb)
{
    int l = threadIdx.x;                 // one wave of 64
    int v0 = (l < nb) ? aux[l] : 0;
    int v1 = (64 + l < nb) ? aux[64 + l] : 0;
    int s0 = v0, s1 = v1;
    for (int off = 1; off < 64; off <<= 1) {
        int u0 = __shfl_up(s0, off);
        int u1 = __shfl_up(s1, off);
        if (l >= off) { s0 += u0; s1 += u1; }
    }
    int tot0 = __shfl(s0, 63);
    if (l < nb) aux[l] = s0 - v0;                       // exclusive
    if (64 + l < nb) aux[64 + l] = tot0 + s1 - v1;
}

__global__ __launch_bounds__(512) void k_scan3(int* __restrict__ start, int* __restrict__ cursor,
                                               const int* __restrict__ aux)
{
    int i = blockIdx.x * 512 + threadIdx.x;
    if (i < NN) {
        int v = start[i] + aux[blockIdx.x];
        start[i] = v;
        cursor[i] = v;
    }
    if (i == 0) start[NN] = EE;
}

__global__ void k_fill(const int* __restrict__ ei, int* __restrict__ cursor, int* __restrict__ sorted)
{
    int e = blockIdx.x * 256 + threadIdx.x;
    if (e >= EE) return;
    int s = ei[e], d = ei[EE + e];
    int pos = atomicAdd(&cursor[d], 1);
    sorted[pos] = s;
}

// ---------------- per-node gather-aggregate, unrolled x4 for memory-level parallelism ----------------
__global__ __launch_bounds__(256) void k_agg(const int* __restrict__ start, const int* __restrict__ sorted,
                                             const float* __restrict__ a_s, const float* __restrict__ a_d,
                                             const __hip_bfloat16* __restrict__ h,
                                             const float* __restrict__ bias_g,
                                             __hip_bfloat16* __restrict__ agg)
{
    int wave = threadIdx.x >> 6;
    int lane = threadIdx.x & 63;
    int d = blockIdx.x * 4 + wave;
    if (d >= NN) return;
    int hh = lane >> 4;                 // head of features 2*lane, 2*lane+1
    float ad = a_d[d * 4 + hh];
    int e0 = start[d], e1 = start[d + 1];

    // self-loop contribution
    float ex = lexp(a_s[d * 4 + hh] + ad);
    unsigned hv = *reinterpret_cast<const unsigned*>(h + (long)d * HC + 2 * lane);
    float acc0 = ex * __uint_as_float(hv << 16);
    float acc1 = ex * __uint_as_float(hv & 0xffff0000u);
    float dsum = ex;

    int e = e0;
    for (; e + 4 <= e1; e += 4) {
        int s0 = sorted[e + 0], s1 = sorted[e + 1], s2 = sorted[e + 2], s3 = sorted[e + 3];
        float as0 = a_s[s0 * 4 + hh], as1 = a_s[s1 * 4 + hh];
        float as2 = a_s[s2 * 4 + hh], as3 = a_s[s3 * 4 + hh];
        unsigned h0 = *reinterpret_cast<const unsigned*>(h + (long)s0 * HC + 2 * lane);
        unsigned h1 = *reinterpret_cast<const unsigned*>(h + (long)s1 * HC + 2 * lane);
        unsigned h2 = *reinterpret_cast<const unsigned*>(h + (long)s2 * HC + 2 * lane);
        unsigned h3 = *reinterpret_cast<const unsigned*>(h + (long)s3 * HC + 2 * lane);
        float x0 = lexp(as0 + ad), x1 = lexp(as1 + ad), x2 = lexp(as2 + ad), x3 = lexp(as3 + ad);
        acc0 += x0 * __uint_as_float(h0 << 16);
        acc1 += x0 * __uint_as_float(h0 & 0xffff0000u);
        acc0 += x1 * __uint_as_float(h1 << 16);
        acc1 += x1 * __uint_as_float(h1 & 0xffff0000u);
        acc0 += x2 * __uint_as_float(h2 << 16);
        acc1 += x2 * __uint_as_float(h2 & 0xffff0000u);
        acc0 += x3 * __uint_as_float(h3 << 16);
        acc1 += x3 * __uint_as_float(h3 & 0xffff0000u);
        dsum += x0 + x1 + x2 + x3;
    }
    for (; e < e1; ++e) {
        int s = sorted[e];
        float xe = lexp(a_s[s * 4 + hh] + ad);
        unsigned hs = *reinterpret_cast<const unsigned*>(h + (long)s * HC + 2 * lane);
        acc0 += xe * __uint_as_float(hs << 16);
        acc1 += xe * __uint_as_float(hs & 0xffff0000u);
        dsum += xe;
    }

    float inv = 1.f / dsum;
    float2 bg = *reinterpret_cast<const float2*>(bias_g + 2 * lane);
    float v0 = acc0 * inv + bg.x;
    float v1 = acc1 * inv + bg.y;
    v0 = v0 > 0.f ? v0 : expm1f(v0);
    v1 = v1 > 0.f ? v1 : expm1f(v1);
    unsigned pk = (unsigned)f2b(v0) | ((unsigned)f2b(v1) << 16);
    *reinterpret_cast<unsigned*>((unsigned short*)agg + (long)d * HC + 2 * lane) = pk;
}

extern "C" void kernel_launch(void* const* d_in, const int* in_sizes, int n_in,
                              void* d_out, int out_size, void* d_ws, size_t ws_size,
                              hipStream_t stream)
{
    const float* x       = (const float*)d_in[0];
    const int*   ei      = (const int*)d_in[1];
    const float* fb      = (const float*)d_in[2];
    const float* Wg      = (const float*)d_in[3];
    const float* bias_g  = (const float*)d_in[4];
    const float* att_src = (const float*)d_in[5];
    const float* att_dst = (const float*)d_in[6];
    const float* W1      = (const float*)d_in[7];
    const float* b1      = (const float*)d_in[8];
    const float* W2      = (const float*)d_in[9];
    const float* b2      = (const float*)d_in[10];
    const float* W3      = (const float*)d_in[11];
    const float* b3      = (const float*)d_in[12];
    float* out = (float*)d_out;
    float* ws = (float*)d_ws;

    // workspace layout (float units) — total 14,167,720 floats = 56.67 MB
    float* a_s = ws + 0;                                        //   200,000 [N,4]
    float* a_d = ws + 200000;                                   //   200,000 [N,4]
    __hip_bfloat16* fbWgT = (__hip_bfloat16*)(ws + 400000);     //   [128][544] bf16 (34,816 f)
    __hip_bfloat16* W1T   = (__hip_bfloat16*)(ws + 434816);     //   [256][128] bf16 (16,384 f)
    __hip_bfloat16* W2T   = (__hip_bfloat16*)(ws + 451200);     //   [128][256] bf16 (16,384 f)
    int* hist   = (int*)(ws + 467584);                          //    50,000 (cursor aliases)
    int* startA = (int*)(ws + 517584);                          //    50,004
    int* aux    = (int*)(ws + 567588);                          //       132
    int* sorted = (int*)(ws + 567720);                          //   800,000
    __hip_bfloat16* hbufB = (__hip_bfloat16*)(ws + 1367720);    //   [N,128] bf16 (3,200,000 f)
    __hip_bfloat16* aggB  = (__hip_bfloat16*)(ws + 4567720);    //   [N,128] bf16 (3,200,000 f)
    __hip_bfloat16* x1B   = (__hip_bfloat16*)(ws + 7767720);    //   [N,256] bf16 (6,400,000 f)
    int* cursor = hist;                                         //   alias (hist dead after scan1)
    __hip_bfloat16* x2B = hbufB;                                //   unused sink for EPI3 C param
    if (ws_size < (size_t)14167720 * sizeof(float)) return;     //   diagnostic: leaves out zeroed

    // zero fbWgT (for K-pad zeros) .. hist (contiguous region)
    hipMemsetAsync(ws + 400000, 0, (size_t)117584 * sizeof(float), stream);

    // fbWgT = (fb @ Wg)^T as bf16, zero-padded K 513->544
    gemm_k<2, float, float, __hip_bfloat16><<<dim3(9, 2), 256, 0, stream>>>(fb, Wg, fbWgT, NFR, HC, NMEL, nullptr);
    // W1T, W2T: transpose-convert weights
    k_trans<<<128, 256, 0, stream>>>(W1, W1T, 128, 256, 128);
    k_trans<<<128, 256, 0, stream>>>(W2, W2T, 256, 128, 256);

    // h = x @ fbWg + fused attention coefficients (a_s, a_d)  [N,128]
    mgemm<4, float, __hip_bfloat16><<<dim3(782, 1), 256, 0, stream>>>(
        x, fbWgT, hbufB, NN, HC, NFR, 544, nullptr, att_src, att_dst, a_s, a_d);

    // CSR build
    k_hist<<<(EE + 255) / 256, 256, 0, stream>>>(ei, hist);
    k_scan1<<<98, 512, 0, stream>>>(hist, startA, aux);
    k_scan2<<<1, 64, 0, stream>>>(aux, 98);
    k_scan3<<<98, 512, 0, stream>>>(startA, cursor, aux);
    k_fill<<<(EE + 255) / 256, 256, 0, stream>>>(ei, cursor, sorted);

    // gather-aggregate: softmax + messages + bias + ELU -> agg bf16
    k_agg<<<(NN + 3) / 4, 256, 0, stream>>>(startA, sorted, a_s, a_d, hbufB, bias_g, aggB);

    // x1 = leaky(agg @ W1 + b1)   [N,256] bf16
    mgemm<1, __hip_bfloat16, __hip_bfloat16><<<dim3(782, 2), 256, 0, stream>>>(
        aggB, W1T, x1B, NN, 256, 128, 128, b1, nullptr, nullptr, nullptr, nullptr);

    // x2 = leaky(x1 @ W2 + b2) + fused final (x2@W3+b3 -> leaky -> softmax -> out)
    mgemm<3, __hip_bfloat16, __hip_bfloat16><<<dim3(782, 1), 256, 0, stream>>>(
        x1B, W2T, x2B, NN, 128, 256, 256, b2, W3, b3, out, nullptr);
}

// Round 12
// 400.704 us; speedup vs baseline: 1.1233x; 1.0205x over previous
//
#include <hip/hip_runtime.h>
#include <hip/hip_bf16.h>

// Problem constants
#define NN 50000
#define EE 800000
#define NFR 513
#define NMEL 128
#define HC 128      // H*C = 4*32

typedef __bf16 bf16x8 __attribute__((ext_vector_type(8)));
typedef float floatx4 __attribute__((ext_vector_type(4)));

// 16-byte load at 4-byte alignment (x rows are 2052 B = 4B-aligned)
struct __attribute__((packed, aligned(4))) u4a { unsigned x, y, z, w; };

__device__ __forceinline__ unsigned short f2b(float f) {   // RNE fp32->bf16 bits
    unsigned u = __float_as_uint(f);
    u = (u + 0x7FFFu + ((u >> 16) & 1u)) >> 16;
    return (unsigned short)u;
}
__device__ __forceinline__ unsigned short f2bu(unsigned u) {  // RNE on raw fp32 bits
    u = (u + 0x7FFFu + ((u >> 16) & 1u)) >> 16;
    return (unsigned short)u;
}
__device__ __forceinline__ float b2f(unsigned short s) {
    return __uint_as_float(((unsigned)s) << 16);
}
__device__ __forceinline__ float lexp(float a) {           // exp(leaky_relu(a, 0.2))
    a = a > 0.f ? a : 0.2f * a;
    return __expf(a);
}

__device__ __forceinline__ float ldf(const float* p, long i) { return p[i]; }
__device__ __forceinline__ void stf(float* p, long i, float v) { p[i] = v; }
__device__ __forceinline__ void stf(__hip_bfloat16* p, long i, float v) {
    ((unsigned short*)p)[i] = f2b(v);
}

// ---------------- fp32 vector GEMM (only for tiny fb@Wg). EPI=2: store bf16 transposed, stride 544 ----------------
#define BM 64
#define BN 64
#define BK 16

template<int EPI, typename TA, typename TB, typename TC>
__global__ __launch_bounds__(256) void gemm_k(const TA* __restrict__ A, const TB* __restrict__ B,
                                              TC* __restrict__ C, int M, int Nn, int K,
                                              const float* __restrict__ bias)
{
    __shared__ float As[BK][BM + 4];
    __shared__ float Bs[BK][BN + 4];
    const int t = threadIdx.x;
    const int row0 = blockIdx.x * BM;
    const int col0 = blockIdx.y * BN;
    const int tc = t & 15, tr = t >> 4;
    float acc[4][4] = {};

    for (int kb = 0; kb < K; kb += BK) {
        #pragma unroll
        for (int i = 0; i < 4; ++i) {
            int idx = i * 256 + t;
            int r = idx >> 4, k = idx & 15;
            int gr = row0 + r, gk = kb + k;
            float v = 0.f;
            if (gr < M && gk < K) v = ldf(A, (long)gr * K + gk);
            As[k][r] = v;
        }
        #pragma unroll
        for (int i = 0; i < 4; ++i) {
            int idx = i * 256 + t;
            int c = idx & 63, k = idx >> 6;
            int gk = kb + k, gc = col0 + c;
            float v = 0.f;
            if (gk < K && gc < Nn) v = ldf(B, (long)gk * Nn + gc);
            Bs[k][c] = v;
        }
        __syncthreads();
        #pragma unroll
        for (int kk = 0; kk < BK; ++kk) {
            float4 av = *reinterpret_cast<const float4*>(&As[kk][tr << 2]);
            float4 bv = *reinterpret_cast<const float4*>(&Bs[kk][tc << 2]);
            float a[4] = {av.x, av.y, av.z, av.w};
            float b[4] = {bv.x, bv.y, bv.z, bv.w};
            #pragma unroll
            for (int i = 0; i < 4; ++i)
                #pragma unroll
                for (int j = 0; j < 4; ++j)
                    acc[i][j] += a[i] * b[j];
        }
        __syncthreads();
    }

    #pragma unroll
    for (int i = 0; i < 4; ++i) {
        int gr = row0 + (tr << 2) + i;
        if (gr >= M) continue;
        #pragma unroll
        for (int j = 0; j < 4; ++j) {
            int gc = col0 + (tc << 2) + j;
            if (gc >= Nn) continue;
            float v = acc[i][j];
            if (EPI == 2) {
                stf(C, (long)gc * 544 + gr, v);      // transposed bf16, zero-padded stride
            } else {
                if (EPI == 1) { v += bias[gc]; v = v > 0.f ? v : 0.01f * v; }
                stf(C, (long)gr * Nn + gc, v);
            }
        }
    }
}

// ---------------- transpose-convert: out[n*KP+k] = bf16(in[k*N+n]) ----------------
__global__ void k_trans(const float* __restrict__ in, __hip_bfloat16* __restrict__ outp,
                        int K, int N, int KP)
{
    int id = blockIdx.x * 256 + threadIdx.x;
    if (id >= N * KP) return;
    int n = id / KP, k = id % KP;
    float v = (k < K) ? in[(long)k * N + n] : 0.f;
    ((unsigned short*)outp)[id] = f2b(v);
}

// ---------------- MFMA bf16 GEMM: C[M,Nn] = A[M,K] @ Bt[Nn,KB]^T ----------------
// R3/R9 structure. R11-verified fusions; only EPI=4 instantiated now
// (mgemm#2/#3 replaced by the fused k_mlp below).
#define PS 40   // LDS row stride in bf16 units (80 B) -> 2-way bank conflicts only (free)

template<typename T> struct ARegs;
template<> struct ARegs<float> { unsigned v[8]; };        // raw fp32 bits
template<> struct ARegs<__hip_bfloat16> { uint4 v; };

__device__ __forceinline__ void loadA_r(const float* __restrict__ A, ARegs<float>& r, int t,
                                        int row0, int M, int K, int kb)
{
    #pragma unroll
    for (int g = 0; g < 2; ++g) {
        int q = g * 256 + t;            // 0..511 quads (64 rows x 8 quads of 16B)
        int row = q >> 3, k4 = (q & 7) * 4;
        int gr = row0 + row, gk = kb + k4;
        unsigned f0 = 0, f1 = 0, f2 = 0, f3 = 0;
        if (gr < M) {
            const float* ap = A + (long)gr * K + gk;
            if (gk + 3 < K) {           // vector path: single dwordx4 at 4B alignment
                u4a u = *reinterpret_cast<const u4a*>(ap);
                f0 = u.x; f1 = u.y; f2 = u.z; f3 = u.w;
            } else {                    // K-boundary chunk (last kb iter only)
                if (gk + 0 < K) f0 = __float_as_uint(ap[0]);
                if (gk + 1 < K) f1 = __float_as_uint(ap[1]);
                if (gk + 2 < K) f2 = __float_as_uint(ap[2]);
            }
        }
        r.v[g * 4 + 0] = f0; r.v[g * 4 + 1] = f1;
        r.v[g * 4 + 2] = f2; r.v[g * 4 + 3] = f3;
    }
}

__device__ __forceinline__ void writeA_r(unsigned short* As, const ARegs<float>& r, int t)
{
    #pragma unroll
    for (int g = 0; g < 2; ++g) {
        int q = g * 256 + t;
        int row = q >> 3, k4 = (q & 7) * 4;
        ushort4 pk;
        pk.x = f2bu(r.v[g * 4 + 0]); pk.y = f2bu(r.v[g * 4 + 1]);
        pk.z = f2bu(r.v[g * 4 + 2]); pk.w = f2bu(r.v[g * 4 + 3]);
        *reinterpret_cast<ushort4*>(&As[row * PS + k4]) = pk;
    }
}

__device__ __forceinline__ void loadA_r(const __hip_bfloat16* __restrict__ A, ARegs<__hip_bfloat16>& r,
                                        int t, int row0, int M, int K, int kb)
{
    int row = t >> 2, k8 = (t & 3) * 8;  // 256 16B-chunks (64 rows x 4)
    int gr = row0 + row;
    uint4 val = make_uint4(0, 0, 0, 0);
    if (gr < M) val = *reinterpret_cast<const uint4*>(A + (long)gr * K + kb + k8);
    r.v = val;
}

__device__ __forceinline__ void writeA_r(unsigned short* As, const ARegs<__hip_bfloat16>& r, int t)
{
    int row = t >> 2, k8 = (t & 3) * 8;
    *reinterpret_cast<uint4*>(&As[row * PS + k8]) = r.v;
}

__device__ __forceinline__ void loadB_r(const __hip_bfloat16* __restrict__ Bt, uint4* bR, int t,
                                        int col0, int Nn, int KB, int kb)
{
    #pragma unroll
    for (int g = 0; g < 2; ++g) {
        int c = g * 256 + t;            // 0..511 16B-chunks (128 rows x 4)
        int row = c >> 2, k8 = (c & 3) * 8;
        int gn = col0 + row;
        uint4 val = make_uint4(0, 0, 0, 0);
        if (gn < Nn) val = *reinterpret_cast<const uint4*>(Bt + (long)gn * KB + kb + k8);
        bR[g] = val;
    }
}

__device__ __forceinline__ void writeB_r(unsigned short* Bs, const uint4* bR, int t)
{
    #pragma unroll
    for (int g = 0; g < 2; ++g) {
        int c = g * 256 + t;
        int row = c >> 2, k8 = (c & 3) * 8;
        *reinterpret_cast<uint4*>(&Bs[row * PS + k8]) = bR[g];
    }
}

// EPI: 4 = plain C + fused attention coeffs (pf1=att_src, pf2=att_dst, po1=a_s, po2=a_d)
template<int EPI, typename TA, typename TC>
__global__ __launch_bounds__(256) void mgemm(const TA* __restrict__ A,
                                             const __hip_bfloat16* __restrict__ Bt,
                                             TC* __restrict__ C,
                                             int M, int Nn, int K, int KB,
                                             const float* __restrict__ bias,
                                             const float* __restrict__ pf1,
                                             const float* __restrict__ pf2,
                                             float* __restrict__ po1,
                                             float* __restrict__ po2)
{
    __shared__ unsigned short As[2][64 * PS];
    __shared__ unsigned short Bs[2][128 * PS];

    const int t = threadIdx.x;
    const int row0 = blockIdx.x * 64;
    const int col0 = blockIdx.y * 128;
    const int wave = t >> 6, lane = t & 63;
    const int wm = (wave >> 1) * 32, wn = (wave & 1) * 64;
    const int lm = lane & 15, kq = lane >> 4;

    floatx4 acc[2][4];
    #pragma unroll
    for (int i = 0; i < 2; ++i)
        #pragma unroll
        for (int j = 0; j < 4; ++j)
            acc[i][j] = 0.f;

    ARegs<TA> aR;
    uint4 bR[2];
    loadA_r(A, aR, t, row0, M, K, 0);
    loadB_r(Bt, bR, t, col0, Nn, KB, 0);

    const int nIter = KB >> 5;
    int b = 0;
    for (int it = 0; it < nIter; ++it) {
        writeA_r(As[b], aR, t);
        writeB_r(Bs[b], bR, t);
        if (it + 1 < nIter) {
            loadA_r(A, aR, t, row0, M, K, (it + 1) * 32);
            loadB_r(Bt, bR, t, col0, Nn, KB, (it + 1) * 32);
        }
        asm volatile("s_waitcnt lgkmcnt(0)" ::: "memory");
        __builtin_amdgcn_s_barrier();
        __builtin_amdgcn_sched_barrier(0);

        bf16x8 af[2], bf[4];
        #pragma unroll
        for (int i = 0; i < 2; ++i)
            af[i] = *reinterpret_cast<const bf16x8*>(&As[b][(wm + i * 16 + lm) * PS + kq * 8]);
        #pragma unroll
        for (int j = 0; j < 4; ++j)
            bf[j] = *reinterpret_cast<const bf16x8*>(&Bs[b][(wn + j * 16 + lm) * PS + kq * 8]);
        #pragma unroll
        for (int i = 0; i < 2; ++i)
            #pragma unroll
            for (int j = 0; j < 4; ++j)
                acc[i][j] = __builtin_amdgcn_mfma_f32_16x16x32_bf16(af[i], bf[j], acc[i][j], 0, 0, 0);
        b ^= 1;
    }

    // ---- epilogue: C write ----
    #pragma unroll
    for (int i = 0; i < 2; ++i) {
        #pragma unroll
        for (int r = 0; r < 4; ++r) {
            int gr = row0 + wm + i * 16 + kq * 4 + r;
            if (gr >= M) continue;
            #pragma unroll
            for (int j = 0; j < 4; ++j) {
                int gc = col0 + wn + j * 16 + lm;
                float v = acc[i][j][r];
                if (EPI == 1) { v += bias[gc]; v = v > 0.f ? v : 0.01f * v; }
                stf(C, (long)gr * Nn + gc, v);
            }
        }
    }

    // ---- EPI=4: fused attention coefficients from acc ----
    if (EPI == 4) {
        float wsv[4], wdv[4];
        #pragma unroll
        for (int j = 0; j < 4; ++j) {
            int gc = wn + j * 16 + lm;      // col0 == 0 for mgemm#1
            wsv[j] = pf1[gc];
            wdv[j] = pf2[gc];
        }
        #pragma unroll
        for (int i = 0; i < 2; ++i) {
            #pragma unroll
            for (int r = 0; r < 4; ++r) {
                float s0 = acc[i][0][r] * wsv[0] + acc[i][1][r] * wsv[1];   // head wn>>5
                float s1 = acc[i][2][r] * wsv[2] + acc[i][3][r] * wsv[3];   // head (wn>>5)+1
                float d0 = acc[i][0][r] * wdv[0] + acc[i][1][r] * wdv[1];
                float d1 = acc[i][2][r] * wdv[2] + acc[i][3][r] * wdv[3];
                #pragma unroll
                for (int m = 1; m < 16; m <<= 1) {
                    s0 += __shfl_xor(s0, m); s1 += __shfl_xor(s1, m);
                    d0 += __shfl_xor(d0, m); d1 += __shfl_xor(d1, m);
                }
                if (lm == 0) {
                    int grow = row0 + wm + i * 16 + kq * 4 + r;
                    if (grow < M) {
                        int h0 = wn >> 5;                 // 0 or 2
                        po1[grow * 4 + h0]     = s0;
                        po1[grow * 4 + h0 + 1] = s1;
                        po2[grow * 4 + h0]     = d0;
                        po2[grow * 4 + h0 + 1] = d1;
                    }
                }
            }
        }
    }
}

// ---------------- fused MLP: out = softmax(leaky(leaky(leaky(agg@W1+b1)@W2+b2)@W3+b3)) ----------------
// Replaces mgemm#2 + mgemm#3 + the x1 51.2MB HBM round-trip. Per 64-row block:
//   phase 1: x1s[64][256] = leaky(agg@W1+b1), two 128-col passes (verified dbuf loop)
//   phase 2: K=256 MFMA loop; A-fragments read DIRECTLY from x1s (no staging);
//            B = W2T staged in the same Bs dbuf.
//   epilogue: x2 -> x2s (aliases x1s, dead by then) -> t<64 matvec+softmax -> out
// LDS: As 10.2 + Bs 20.5 + x1s 64x264 33.8 + w3s 5.1 = 69.6 KB -> 2 blocks/CU.
// Race audit: dbuf safety across cp-halves/phases holds via the <=1-buffer-distance
// barrier invariant; explicit __syncthreads at the phase transition (x1s publish),
// before x2s aliases x1s, and before the final matvec. All barriers uniform.
// x1s stride 264 -> rows 528B (16B-aligned for ds_read_b128), ~2-way bank aliasing.
__global__ __launch_bounds__(256) void k_mlp(const __hip_bfloat16* __restrict__ A,
                                             const __hip_bfloat16* __restrict__ W1t,
                                             const __hip_bfloat16* __restrict__ W2t,
                                             const float* __restrict__ b1,
                                             const float* __restrict__ b2,
                                             const float* __restrict__ W3,
                                             const float* __restrict__ b3,
                                             float* __restrict__ out, int M)
{
    __shared__ unsigned short As[2][64 * PS];
    __shared__ unsigned short Bs[2][128 * PS];
    __shared__ unsigned short x1s[64 * 264];
    __shared__ float w3s[1280];

    const int t = threadIdx.x;
    const int row0 = blockIdx.x * 64;
    const int wave = t >> 6, lane = t & 63;
    const int wm = (wave >> 1) * 32, wn = (wave & 1) * 64;
    const int lm = lane & 15, kq = lane >> 4;

    for (int i = t; i < 1280; i += 256) w3s[i] = W3[i];    // [128][10] fp32

    ARegs<__hip_bfloat16> aR;
    uint4 bR[2];

    // ---------- phase 1: x1s = leaky(agg @ W1 + b1), halves cp=0,1 ----------
    #pragma unroll 1
    for (int cp = 0; cp < 2; ++cp) {
        floatx4 acc[2][4];
        #pragma unroll
        for (int i = 0; i < 2; ++i)
            #pragma unroll
            for (int j = 0; j < 4; ++j) acc[i][j] = 0.f;

        loadA_r(A, aR, t, row0, M, 128, 0);
        loadB_r(W1t, bR, t, cp * 128, 256, 128, 0);
        int b = 0;
        #pragma unroll 1
        for (int it = 0; it < 4; ++it) {
            writeA_r(As[b], aR, t);
            writeB_r(Bs[b], bR, t);
            if (it + 1 < 4) {
                loadA_r(A, aR, t, row0, M, 128, (it + 1) * 32);
                loadB_r(W1t, bR, t, cp * 128, 256, 128, (it + 1) * 32);
            }
            asm volatile("s_waitcnt lgkmcnt(0)" ::: "memory");
            __builtin_amdgcn_s_barrier();
            __builtin_amdgcn_sched_barrier(0);

            bf16x8 af[2], bf[4];
            #pragma unroll
            for (int i = 0; i < 2; ++i)
                af[i] = *reinterpret_cast<const bf16x8*>(&As[b][(wm + i * 16 + lm) * PS + kq * 8]);
            #pragma unroll
            for (int j = 0; j < 4; ++j)
                bf[j] = *reinterpret_cast<const bf16x8*>(&Bs[b][(wn + j * 16 + lm) * PS + kq * 8]);
            #pragma unroll
            for (int i = 0; i < 2; ++i)
                #pragma unroll
                for (int j = 0; j < 4; ++j)
                    acc[i][j] = __builtin_amdgcn_mfma_f32_16x16x32_bf16(af[i], bf[j], acc[i][j], 0, 0, 0);
            b ^= 1;
        }
        // write this half's x1 columns (per-wave-owned region; read only after barrier)
        #pragma unroll
        for (int i = 0; i < 2; ++i)
            #pragma unroll
            for (int r = 0; r < 4; ++r) {
                int lrow = wm + i * 16 + kq * 4 + r;
                #pragma unroll
                for (int j = 0; j < 4; ++j) {
                    int gc = cp * 128 + wn + j * 16 + lm;
                    float v = acc[i][j][r] + b1[gc];
                    v = v > 0.f ? v : 0.01f * v;
                    x1s[lrow * 264 + gc] = f2b(v);
                }
            }
    }

    // prefetch phase-2 first B tile (register loads, LDS-independent), publish x1s
    loadB_r(W2t, bR, t, 0, 128, 256, 0);
    __syncthreads();

    // ---------- phase 2: x2 = leaky(x1 @ W2 + b2), K=256 ----------
    floatx4 acc[2][4];
    #pragma unroll
    for (int i = 0; i < 2; ++i)
        #pragma unroll
        for (int j = 0; j < 4; ++j) acc[i][j] = 0.f;

    int b = 0;
    #pragma unroll 1
    for (int it = 0; it < 8; ++it) {
        writeB_r(Bs[b], bR, t);
        if (it + 1 < 8) loadB_r(W2t, bR, t, 0, 128, 256, (it + 1) * 32);
        asm volatile("s_waitcnt lgkmcnt(0)" ::: "memory");
        __builtin_amdgcn_s_barrier();
        __builtin_amdgcn_sched_barrier(0);

        bf16x8 af[2], bf[4];
        #pragma unroll
        for (int i = 0; i < 2; ++i)
            af[i] = *reinterpret_cast<const bf16x8*>(&x1s[(wm + i * 16 + lm) * 264 + it * 32 + kq * 8]);
        #pragma unroll
        for (int j = 0; j < 4; ++j)
            bf[j] = *reinterpret_cast<const bf16x8*>(&Bs[b][(wn + j * 16 + lm) * PS + kq * 8]);
        #pragma unroll
        for (int i = 0; i < 2; ++i)
            #pragma unroll
            for (int j = 0; j < 4; ++j)
                acc[i][j] = __builtin_amdgcn_mfma_f32_16x16x32_bf16(af[i], bf[j], acc[i][j], 0, 0, 0);
        b ^= 1;
    }

    __syncthreads();                       // all waves' x1s reads drained before aliasing
    unsigned short* x2s = x1s;             // x2 tile, stride 130 (fits: 8317 < 16896)
    #pragma unroll
    for (int i = 0; i < 2; ++i)
        #pragma unroll
        for (int r = 0; r < 4; ++r) {
            int lrow = wm + i * 16 + kq * 4 + r;
            #pragma unroll
            for (int j = 0; j < 4; ++j) {
                int gc = wn + j * 16 + lm;
                float v = acc[i][j][r] + b2[gc];
                v = v > 0.f ? v : 0.01f * v;
                x2s[lrow * 130 + gc] = f2b(v);
            }
        }
    __syncthreads();

    // ---------- final: out = softmax(leaky(x2 @ W3 + b3)) ----------
    if (t < 64) {
        int grow = row0 + t;
        if (grow < M) {
            float l[10];
            #pragma unroll
            for (int j = 0; j < 10; ++j) l[j] = b3[j];
            #pragma unroll 8
            for (int c = 0; c < 128; ++c) {
                float xv = b2f(x2s[t * 130 + c]);
                const float* wr = &w3s[c * 10];
                #pragma unroll
                for (int j = 0; j < 10; ++j) l[j] += xv * wr[j];
            }
            float m = -1e30f;
            #pragma unroll
            for (int j = 0; j < 10; ++j) {
                float v = l[j];
                v = v > 0.f ? v : 0.01f * v;
                l[j] = v;
                m = fmaxf(m, v);
            }
            float sum = 0.f;
            #pragma unroll
            for (int j = 0; j < 10; ++j) { l[j] = __expf(l[j] - m); sum += l[j]; }
            float inv = 1.f / sum;
            #pragma unroll
            for (int j = 0; j < 10; ++j) out[(long)grow * 10 + j] = l[j] * inv;
        }
    }
}

// ---------------- CSR build: histogram -> scan -> fill ----------------
__global__ void k_hist(const int* __restrict__ ei, int* __restrict__ hist)
{
    int e = blockIdx.x * 256 + threadIdx.x;
    if (e < EE) atomicAdd(&hist[ei[EE + e]], 1);
}

__global__ __launch_bounds__(512) void k_scan1(const int* __restrict__ hist, int* __restrict__ start,
                                               int* __restrict__ aux)
{
    __shared__ int sm[512];
    int t = threadIdx.x, i = blockIdx.x * 512 + t;
    int v = (i < NN) ? hist[i] : 0;
    sm[t] = v;
    __syncthreads();
    for (int off = 1; off < 512; off <<= 1) {
        int x = (t >= off) ? sm[t - off] : 0;
        __syncthreads();
        sm[t] += x;
        __syncthreads();
    }
    if (i < NN) start[i] = sm[t] - v;   // exclusive
    if (t == 511) aux[blockIdx.x] = sm[511];
}

// wave-parallel exclusive scan of 98 block sums
__global__ void k_scan2(int* __restrict__ aux, int nb)
{
    int l = threadIdx.x;                 // one wave of 64
    int v0 = (l < nb) ? aux[l] : 0;
    int v1 = (64 + l < nb) ? aux[64 + l] : 0;
    int s0 = v0, s1 = v1;
    for (int off = 1; off < 64; off <<= 1) {
        int u0 = __shfl_up(s0, off);
        int u1 = __shfl_up(s1, off);
        if (l >= off) { s0 += u0; s1 += u1; }
    }
    int tot0 = __shfl(s0, 63);
    if (l < nb) aux[l] = s0 - v0;                       // exclusive
    if (64 + l < nb) aux[64 + l] = tot0 + s1 - v1;
}

__global__ __launch_bounds__(512) void k_scan3(int* __restrict__ start, int* __restrict__ cursor,
                                               const int* __restrict__ aux)
{
    int i = blockIdx.x * 512 + threadIdx.x;
    if (i < NN) {
        int v = start[i] + aux[blockIdx.x];
        start[i] = v;
        cursor[i] = v;
    }
    if (i == 0) start[NN] = EE;
}

__global__ void k_fill(const int* __restrict__ ei, int* __restrict__ cursor, int* __restrict__ sorted)
{
    int e = blockIdx.x * 256 + threadIdx.x;
    if (e >= EE) return;
    int s = ei[e], d = ei[EE + e];
    int pos = atomicAdd(&cursor[d], 1);
    sorted[pos] = s;
}

// ---------------- per-node gather-aggregate, unrolled x4 for memory-level parallelism ----------------
__global__ __launch_bounds__(256) void k_agg(const int* __restrict__ start, const int* __restrict__ sorted,
                                             const float* __restrict__ a_s, const float* __restrict__ a_d,
                                             const __hip_bfloat16* __restrict__ h,
                                             const float* __restrict__ bias_g,
                                             __hip_bfloat16* __restrict__ agg)
{
    int wave = threadIdx.x >> 6;
    int lane = threadIdx.x & 63;
    int d = blockIdx.x * 4 + wave;
    if (d >= NN) return;
    int hh = lane >> 4;                 // head of features 2*lane, 2*lane+1
    float ad = a_d[d * 4 + hh];
    int e0 = start[d], e1 = start[d + 1];

    // self-loop contribution
    float ex = lexp(a_s[d * 4 + hh] + ad);
    unsigned hv = *reinterpret_cast<const unsigned*>(h + (long)d * HC + 2 * lane);
    float acc0 = ex * __uint_as_float(hv << 16);
    float acc1 = ex * __uint_as_float(hv & 0xffff0000u);
    float dsum = ex;

    int e = e0;
    for (; e + 4 <= e1; e += 4) {
        int s0 = sorted[e + 0], s1 = sorted[e + 1], s2 = sorted[e + 2], s3 = sorted[e + 3];
        float as0 = a_s[s0 * 4 + hh], as1 = a_s[s1 * 4 + hh];
        float as2 = a_s[s2 * 4 + hh], as3 = a_s[s3 * 4 + hh];
        unsigned h0 = *reinterpret_cast<const unsigned*>(h + (long)s0 * HC + 2 * lane);
        unsigned h1 = *reinterpret_cast<const unsigned*>(h + (long)s1 * HC + 2 * lane);
        unsigned h2 = *reinterpret_cast<const unsigned*>(h + (long)s2 * HC + 2 * lane);
        unsigned h3 = *reinterpret_cast<const unsigned*>(h + (long)s3 * HC + 2 * lane);
        float x0 = lexp(as0 + ad), x1 = lexp(as1 + ad), x2 = lexp(as2 + ad), x3 = lexp(as3 + ad);
        acc0 += x0 * __uint_as_float(h0 << 16);
        acc1 += x0 * __uint_as_float(h0 & 0xffff0000u);
        acc0 += x1 * __uint_as_float(h1 << 16);
        acc1 += x1 * __uint_as_float(h1 & 0xffff0000u);
        acc0 += x2 * __uint_as_float(h2 << 16);
        acc1 += x2 * __uint_as_float(h2 & 0xffff0000u);
        acc0 += x3 * __uint_as_float(h3 << 16);
        acc1 += x3 * __uint_as_float(h3 & 0xffff0000u);
        dsum += x0 + x1 + x2 + x3;
    }
    for (; e < e1; ++e) {
        int s = sorted[e];
        float xe = lexp(a_s[s * 4 + hh] + ad);
        unsigned hs = *reinterpret_cast<const unsigned*>(h + (long)s * HC + 2 * lane);
        acc0 += xe * __uint_as_float(hs << 16);
        acc1 += xe * __uint_as_float(hs & 0xffff0000u);
        dsum += xe;
    }

    float inv = 1.f / dsum;
    float2 bg = *reinterpret_cast<const float2*>(bias_g + 2 * lane);
    float v0 = acc0 * inv + bg.x;
    float v1 = acc1 * inv + bg.y;
    v0 = v0 > 0.f ? v0 : expm1f(v0);
    v1 = v1 > 0.f ? v1 : expm1f(v1);
    unsigned pk = (unsigned)f2b(v0) | ((unsigned)f2b(v1) << 16);
    *reinterpret_cast<unsigned*>((unsigned short*)agg + (long)d * HC + 2 * lane) = pk;
}

extern "C" void kernel_launch(void* const* d_in, const int* in_sizes, int n_in,
                              void* d_out, int out_size, void* d_ws, size_t ws_size,
                              hipStream_t stream)
{
    const float* x       = (const float*)d_in[0];
    const int*   ei      = (const int*)d_in[1];
    const float* fb      = (const float*)d_in[2];
    const float* Wg      = (const float*)d_in[3];
    const float* bias_g  = (const float*)d_in[4];
    const float* att_src = (const float*)d_in[5];
    const float* att_dst = (const float*)d_in[6];
    const float* W1      = (const float*)d_in[7];
    const float* b1      = (const float*)d_in[8];
    const float* W2      = (const float*)d_in[9];
    const float* b2      = (const float*)d_in[10];
    const float* W3      = (const float*)d_in[11];
    const float* b3      = (const float*)d_in[12];
    float* out = (float*)d_out;
    float* ws = (float*)d_ws;

    // workspace layout (float units)
    float* a_s = ws + 0;                                        //   200,000 [N,4]
    float* a_d = ws + 200000;                                   //   200,000 [N,4]
    __hip_bfloat16* fbWgT = (__hip_bfloat16*)(ws + 400000);     //   [128][544] bf16 (34,816 f)
    __hip_bfloat16* W1T   = (__hip_bfloat16*)(ws + 434816);     //   [256][128] bf16 (16,384 f)
    __hip_bfloat16* W2T   = (__hip_bfloat16*)(ws + 451200);     //   [128][256] bf16 (16,384 f)
    int* hist   = (int*)(ws + 467584);                          //    50,000 (cursor aliases)
    int* startA = (int*)(ws + 517584);                          //    50,004
    int* aux    = (int*)(ws + 567588);                          //       132
    int* sorted = (int*)(ws + 567720);                          //   800,000
    __hip_bfloat16* hbufB = (__hip_bfloat16*)(ws + 1367720);    //   [N,128] bf16 (3,200,000 f)
    __hip_bfloat16* aggB  = (__hip_bfloat16*)(ws + 4567720);    //   [N,128] bf16 (3,200,000 f)
    int* cursor = hist;                                         //   alias (hist dead after scan1)
    if (ws_size < (size_t)14167720 * sizeof(float)) return;     //   diagnostic: leaves out zeroed

    // zero fbWgT (for K-pad zeros) .. hist (contiguous region)
    hipMemsetAsync(ws + 400000, 0, (size_t)117584 * sizeof(float), stream);

    // fbWgT = (fb @ Wg)^T as bf16, zero-padded K 513->544
    gemm_k<2, float, float, __hip_bfloat16><<<dim3(9, 2), 256, 0, stream>>>(fb, Wg, fbWgT, NFR, HC, NMEL, nullptr);
    // W1T, W2T: transpose-convert weights
    k_trans<<<128, 256, 0, stream>>>(W1, W1T, 128, 256, 128);
    k_trans<<<128, 256, 0, stream>>>(W2, W2T, 256, 128, 256);

    // h = x @ fbWg + fused attention coefficients (a_s, a_d)  [N,128]
    mgemm<4, float, __hip_bfloat16><<<dim3(782, 1), 256, 0, stream>>>(
        x, fbWgT, hbufB, NN, HC, NFR, 544, nullptr, att_src, att_dst, a_s, a_d);

    // CSR build
    k_hist<<<(EE + 255) / 256, 256, 0, stream>>>(ei, hist);
    k_scan1<<<98, 512, 0, stream>>>(hist, startA, aux);
    k_scan2<<<1, 64, 0, stream>>>(aux, 98);
    k_scan3<<<98, 512, 0, stream>>>(startA, cursor, aux);
    k_fill<<<(EE + 255) / 256, 256, 0, stream>>>(ei, cursor, sorted);

    // gather-aggregate: softmax + messages + bias + ELU -> agg bf16
    k_agg<<<(NN + 3) / 4, 256, 0, stream>>>(startA, sorted, a_s, a_d, hbufB, bias_g, aggB);

    // fused MLP: agg -> (W1,b1,leaky) -> (W2,b2,leaky) -> (W3,b3,leaky) -> softmax -> out
    k_mlp<<<782, 256, 0, stream>>>(aggB, W1T, W2T, b1, b2, W3, b3, out, NN);
}